// Round 11
// baseline (663.471 us; speedup 1.0000x reference)
//
#include <hip/hip_runtime.h>
#include <stdint.h>

#define D_MODEL   1024
#define D_HIDDEN  4096
#define NBANKS    16
#define NTOK      4096      // 4 * 1024 tokens

#define BM 256
#define BN 128
#define BK 32
#define TBX (BM * BK)       // A buffer elems (16 KB bf16)
#define TBW (BN * BK)       // B buffer elems (8 KB bf16)
#define KS2 4               // K-split for gemm2

typedef __attribute__((ext_vector_type(8))) short bf16x8;
typedef __attribute__((ext_vector_type(4))) float f32x4;
typedef __attribute__((ext_vector_type(4))) unsigned int u32x4;
typedef __attribute__((ext_vector_type(2))) unsigned int u32x2;

__device__ __forceinline__ unsigned short f2bf(float f) {
  unsigned u = __builtin_bit_cast(unsigned, f);
  u += 0x7FFFu + ((u >> 16) & 1u);
  return (unsigned short)(u >> 16);
}

__device__ __forceinline__ unsigned cvtpk(float lo, float hi) {
  unsigned r;
  asm("v_cvt_pk_bf16_f32 %0, %1, %2" : "=v"(r) : "v"(lo), "v"(hi));
  return r;
}

// LDS elem index for [rows][32] bf16 tiles (64-B rows, 4x 16B chunks).
// chunk ^= (r>>1)&3. Enumerated at floor: frag b128 reads (16 rows x chunk fg),
// A b128 writes (row=tid, 4 chunks). B b64 writes (rows 4u+i) are 2x (accepted).
__device__ __forceinline__ int sidx(int r, int k) {
  return (r << 5) + ((((k >> 3) ^ ((r >> 1) & 3)) << 3) | (k & 7));
}

// ---------------- zero output + counts ----------------
__global__ __launch_bounds__(256) void zero_out_k(float4* __restrict__ out4,
                                                  int* __restrict__ counts) {
  size_t i = (size_t)blockIdx.x * 256 + threadIdx.x;
  out4[i] = make_float4(0.f, 0.f, 0.f, 0.f);
  if (blockIdx.x == 0 && threadIdx.x < NBANKS) counts[threadIdx.x] = 0;
}

// ---------------- X f32 -> bf16 pre-convert ----------------
__global__ __launch_bounds__(256) void cvtx_k(const float* __restrict__ X,
                                              unsigned short* __restrict__ Xb) {
  const size_t i = ((size_t)blockIdx.x * 256 + threadIdx.x) * 8;
  const float4 a = *(const float4*)(X + i);
  const float4 b = *(const float4*)(X + i + 4);
  u32x4 v;
  v[0] = cvtpk(a.x, a.y); v[1] = cvtpk(a.z, a.w);
  v[2] = cvtpk(b.x, b.y); v[3] = cvtpk(b.z, b.w);
  *(u32x4*)(Xb + i) = v;
}

// ---------------- router ----------------
__global__ __launch_bounds__(64) void router_k(const float* __restrict__ x,
                                               const float* __restrict__ Wr,
                                               const float* __restrict__ br,
                                               int* __restrict__ topIdx,
                                               float* __restrict__ topGate) {
  const int t = blockIdx.x;
  const int l = threadIdx.x;
  const float* xr = x + (size_t)t * D_MODEL;

  float acc[NBANKS];
#pragma unroll
  for (int e = 0; e < NBANKS; ++e) acc[e] = 0.f;

  for (int d = l; d < D_MODEL; d += 64) {
    const float xv = xr[d];
    const float* wrow = Wr + (size_t)d * NBANKS;
#pragma unroll
    for (int e = 0; e < NBANKS; ++e) acc[e] += xv * wrow[e];
  }
#pragma unroll
  for (int e = 0; e < NBANKS; ++e) {
#pragma unroll
    for (int m = 1; m < 64; m <<= 1) acc[e] += __shfl_xor(acc[e], m, 64);
  }
#pragma unroll
  for (int e = 0; e < NBANKS; ++e) acc[e] += br[e];

  if (l == 0) {
    float mx = acc[0];
#pragma unroll
    for (int e = 1; e < NBANKS; ++e) mx = fmaxf(mx, acc[e]);
    float p[NBANKS];
    float s = 0.f;
#pragma unroll
    for (int e = 0; e < NBANKS; ++e) { p[e] = expf(acc[e] - mx); s += p[e]; }
    int i0 = 0; float v0 = p[0];
#pragma unroll
    for (int e = 1; e < NBANKS; ++e) if (p[e] > v0) { v0 = p[e]; i0 = e; }
    int i1 = -1; float v1 = -1.f;
#pragma unroll
    for (int e = 0; e < NBANKS; ++e) if (e != i0 && p[e] > v1) { v1 = p[e]; i1 = e; }
    const float inv = 1.f / s;
    topIdx[2 * t]     = i0;
    topIdx[2 * t + 1] = i1;
    topGate[2 * t]     = v0 * inv;
    topGate[2 * t + 1] = v1 * inv;
  }
}

// ---------------- build per-bank token lists ----------------
__global__ __launch_bounds__(256) void build_lists_k(const int* __restrict__ topIdx,
                                                     const float* __restrict__ topGate,
                                                     int* __restrict__ counts,
                                                     int* __restrict__ rowlist,
                                                     float* __restrict__ gatelist) {
  const int t = blockIdx.x * 256 + threadIdx.x;
  if (t >= NTOK) return;
#pragma unroll
  for (int k = 0; k < 2; ++k) {
    const int e = topIdx[2 * t + k];
    const int p = atomicAdd(&counts[e], 1);
    rowlist[e * NTOK + p]  = t;
    gatelist[e * NTOK + p] = topGate[2 * t + k];
  }
}

__global__ void scan_k(const int* __restrict__ counts, int* __restrict__ bankOff) {
  if (threadIdx.x == 0) {
    int s = 0;
#pragma unroll
    for (int e = 0; e < NBANKS; ++e) { bankOff[e] = s; s += counts[e]; }
    bankOff[NBANKS] = s;
  }
}

// ---------------- GEMM1: H = relu(gather(Xb) @ W1[e] + b1[e]) ----------------
// Block 256m x 128n, 4 waves (2m x 2n), wave tile 128x64, BK=32, 2-phase dbuf.
__global__ __launch_bounds__(256, 2) void gemm1_k(const unsigned short* __restrict__ Xb,
                                                  const float* __restrict__ W1,
                                                  const float* __restrict__ b1,
                                                  const int* __restrict__ counts,
                                                  const int* __restrict__ bankOff,
                                                  const int* __restrict__ rowlist,
                                                  unsigned short* __restrict__ H) {
  // nwg = 16m x 32n x 16e = 8192; chunked XCD swizzle (C = 1024), m-fastest
  const int orig = (blockIdx.x & 7) * 1024 + (blockIdx.x >> 3);
  const int mI = orig & 15;
  const int nI = (orig >> 4) & 31;
  const int e  = orig >> 9;

  const int cnt = counts[e];
  const int m0  = mI * BM;
  if (m0 >= cnt) return;
  const int n0  = nI * BN;

  const int tid  = threadIdx.x;
  const int lane = tid & 63;
  const int w    = tid >> 6;
  const int wm   = (w >> 1) * 128;
  const int wn   = (w & 1) * 64;
  const int fr   = lane & 15;
  const int fg   = lane >> 4;

  __shared__ unsigned short Xs[2 * TBX];
  __shared__ unsigned short Ws[2 * TBW];

  // A staging: 1 row per thread (row = tid), 32 bf16 = 4 b128
  const int gi  = min(m0 + tid, cnt - 1);
  const int tok = rowlist[e * NTOK + gi];
  const unsigned short* Asrc = Xb + (size_t)tok * D_MODEL;
  int xo[4];
#pragma unroll
  for (int j = 0; j < 4; ++j) xo[j] = sidx(tid, 8 * j);

  // B staging: 4n x 4k micro-transpose; n4 = 4*(tid&31), k4 = 4*(tid>>5)
  const int n4 = 4 * (tid & 31);
  const int k4 = 4 * (tid >> 5);
  const float* Bsrc = W1 + (size_t)e * D_MODEL * D_HIDDEN + (size_t)k4 * D_HIDDEN + n0 + n4;
  int wo[4];
#pragma unroll
  for (int i = 0; i < 4; ++i) wo[i] = sidx(n4 + i, k4);

  // fragment read offsets
  int aoff[8], boff[4];
#pragma unroll
  for (int i = 0; i < 8; ++i) aoff[i] = sidx(wm + i * 16 + fr, fg * 8);
#pragma unroll
  for (int i = 0; i < 4; ++i) boff[i] = sidx(wn + i * 16 + fr, fg * 8);

  bf16x8 ra[4];
  float rbf[4][4];

  f32x4 acc[8][4];
#pragma unroll
  for (int i = 0; i < 8; ++i)
#pragma unroll
    for (int j = 0; j < 4; ++j)
#pragma unroll
      for (int r = 0; r < 4; ++r) acc[i][j][r] = 0.f;

  unsigned short* xc = &Xs[0];     unsigned short* wc = &Ws[0];
  unsigned short* xn = &Xs[TBX];   unsigned short* wn_ = &Ws[TBW];

  auto LOAD = [&](int t) {
    const unsigned short* ap = Asrc + t * BK;
#pragma unroll
    for (int j = 0; j < 4; ++j) ra[j] = *(const bf16x8*)(ap + 8 * j);
    const float* bp = Bsrc + (size_t)t * BK * D_HIDDEN;
#pragma unroll
    for (int kk = 0; kk < 4; ++kk)
      *(float4*)&rbf[kk][0] = *(const float4*)(bp + (size_t)kk * D_HIDDEN);
  };

  auto WRITE = [&](unsigned short* xs, unsigned short* ws) {
#pragma unroll
    for (int j = 0; j < 4; ++j) *(bf16x8*)(xs + xo[j]) = ra[j];
#pragma unroll
    for (int i = 0; i < 4; ++i) {
      u32x2 v;
      v[0] = cvtpk(rbf[0][i], rbf[1][i]);
      v[1] = cvtpk(rbf[2][i], rbf[3][i]);
      *(u32x2*)(ws + wo[i]) = v;
    }
  };

  auto COMPUTE = [&](const unsigned short* xs, const unsigned short* ws) {
    bf16x8 af[8];
#pragma unroll
    for (int mb = 0; mb < 8; ++mb) af[mb] = *(const bf16x8*)(xs + aoff[mb]);
    __builtin_amdgcn_s_setprio(1);
#pragma unroll
    for (int nb = 0; nb < 4; ++nb) {
      const bf16x8 bb = *(const bf16x8*)(ws + boff[nb]);
#pragma unroll
      for (int mb = 0; mb < 8; ++mb)
        acc[mb][nb] = __builtin_amdgcn_mfma_f32_16x16x32_bf16(af[mb], bb, acc[mb][nb], 0, 0, 0);
    }
    __builtin_amdgcn_s_setprio(0);
  };

  const int NT = D_MODEL / BK;   // 32
  LOAD(0);
  WRITE(xc, wc);
  __syncthreads();
#pragma unroll 1
  for (int t = 0; t < NT; ++t) {
    if (t + 1 < NT) LOAD(t + 1);
    __builtin_amdgcn_sched_barrier(0);   // keep loads above compute
    COMPUTE(xc, wc);
    if (t + 1 < NT) WRITE(xn, wn_);
    __syncthreads();
    unsigned short* t0 = xc; xc = xn;  xn  = t0;
    unsigned short* t1 = wc; wc = wn_; wn_ = t1;
  }

  // epilogue: relu(acc + b1) -> H (bf16)
  const int hb = bankOff[e] + m0;
  const int rq = fg * 4;
#pragma unroll
  for (int nb = 0; nb < 4; ++nb) {
    const int col = n0 + wn + nb * 16 + fr;
    const float bias = b1[e * D_HIDDEN + col];
#pragma unroll
    for (int mb = 0; mb < 8; ++mb)
#pragma unroll
      for (int r = 0; r < 4; ++r) {
        const int rowT = wm + mb * 16 + rq + r;
        if (m0 + rowT < cnt) {
          float v = acc[mb][nb][r] + bias;
          v = fmaxf(v, 0.f);
          H[(size_t)(hb + rowT) * D_HIDDEN + col] = f2bf(v);
        }
      }
  }
}

// ---------------- GEMM2: out += gate * (H @ W2[e] + b2[e]), K-split x4 ----
__global__ __launch_bounds__(256, 2) void gemm2_k(const unsigned short* __restrict__ H,
                                                  const float* __restrict__ W2,
                                                  const float* __restrict__ b2,
                                                  const int* __restrict__ counts,
                                                  const int* __restrict__ bankOff,
                                                  const int* __restrict__ rowlist,
                                                  const float* __restrict__ gatelist,
                                                  float* __restrict__ out) {
  // nwg = 16m x 8n x 64(e,kc) = 8192; chunked XCD swizzle (C = 1024), m-fastest
  const int orig = (blockIdx.x & 7) * 1024 + (blockIdx.x >> 3);
  const int mI = orig & 15;
  const int nI = (orig >> 4) & 7;
  const int z  = orig >> 7;
  const int e  = z >> 2;
  const int kc = z & 3;

  const int cnt = counts[e];
  const int m0  = mI * BM;
  if (m0 >= cnt) return;
  const int n0  = nI * BN;
  const int kc0 = kc * (D_HIDDEN / KS2);   // 0, 1024, 2048, 3072

  const int tid  = threadIdx.x;
  const int lane = tid & 63;
  const int w    = tid >> 6;
  const int wm   = (w >> 1) * 128;
  const int wn   = (w & 1) * 64;
  const int fr   = lane & 15;
  const int fg   = lane >> 4;

  __shared__ unsigned short Xs[2 * TBX];
  __shared__ unsigned short Ws[2 * TBW];

  const int hb = bankOff[e];
  const int gi = hb + min(m0 + tid, cnt - 1);
  const unsigned short* Asrc = H + (size_t)gi * D_HIDDEN + kc0;
  int xo[4];
#pragma unroll
  for (int j = 0; j < 4; ++j) xo[j] = sidx(tid, 8 * j);

  const int n4 = 4 * (tid & 31);
  const int k4 = 4 * (tid >> 5);
  const float* Bsrc = W2 + (size_t)e * D_HIDDEN * D_MODEL + (size_t)(kc0 + k4) * D_MODEL + n0 + n4;
  int wo[4];
#pragma unroll
  for (int i = 0; i < 4; ++i) wo[i] = sidx(n4 + i, k4);

  int aoff[8], boff[4];
#pragma unroll
  for (int i = 0; i < 8; ++i) aoff[i] = sidx(wm + i * 16 + fr, fg * 8);
#pragma unroll
  for (int i = 0; i < 4; ++i) boff[i] = sidx(wn + i * 16 + fr, fg * 8);

  bf16x8 ra[4];
  float rbf[4][4];

  f32x4 acc[8][4];
#pragma unroll
  for (int i = 0; i < 8; ++i)
#pragma unroll
    for (int j = 0; j < 4; ++j)
#pragma unroll
      for (int r = 0; r < 4; ++r) acc[i][j][r] = 0.f;

  unsigned short* xc = &Xs[0];     unsigned short* wc = &Ws[0];
  unsigned short* xn = &Xs[TBX];   unsigned short* wn_ = &Ws[TBW];

  auto LOAD = [&](int t) {
    const unsigned short* ap = Asrc + t * BK;
#pragma unroll
    for (int j = 0; j < 4; ++j) ra[j] = *(const bf16x8*)(ap + 8 * j);
    const float* bp = Bsrc + (size_t)t * BK * D_MODEL;
#pragma unroll
    for (int kk = 0; kk < 4; ++kk)
      *(float4*)&rbf[kk][0] = *(const float4*)(bp + (size_t)kk * D_MODEL);
  };

  auto WRITE = [&](unsigned short* xs, unsigned short* ws) {
#pragma unroll
    for (int j = 0; j < 4; ++j) *(bf16x8*)(xs + xo[j]) = ra[j];
#pragma unroll
    for (int i = 0; i < 4; ++i) {
      u32x2 v;
      v[0] = cvtpk(rbf[0][i], rbf[1][i]);
      v[1] = cvtpk(rbf[2][i], rbf[3][i]);
      *(u32x2*)(ws + wo[i]) = v;
    }
  };

  auto COMPUTE = [&](const unsigned short* xs, const unsigned short* ws) {
    bf16x8 af[8];
#pragma unroll
    for (int mb = 0; mb < 8; ++mb) af[mb] = *(const bf16x8*)(xs + aoff[mb]);
    __builtin_amdgcn_s_setprio(1);
#pragma unroll
    for (int nb = 0; nb < 4; ++nb) {
      const bf16x8 bb = *(const bf16x8*)(ws + boff[nb]);
#pragma unroll
      for (int mb = 0; mb < 8; ++mb)
        acc[mb][nb] = __builtin_amdgcn_mfma_f32_16x16x32_bf16(af[mb], bb, acc[mb][nb], 0, 0, 0);
    }
    __builtin_amdgcn_s_setprio(0);
  };

  const int NT = (D_HIDDEN / KS2) / BK;   // 32
  LOAD(0);
  WRITE(xc, wc);
  __syncthreads();
#pragma unroll 1
  for (int t = 0; t < NT; ++t) {
    if (t + 1 < NT) LOAD(t + 1);
    __builtin_amdgcn_sched_barrier(0);
    COMPUTE(xc, wc);
    if (t + 1 < NT) WRITE(xn, wn_);
    __syncthreads();
    unsigned short* t0 = xc; xc = xn;  xn  = t0;
    unsigned short* t1 = wc; wc = wn_; wn_ = t1;
  }

  // epilogue: out[tok] += gate * (acc [+ b2 if kc==0])
  const int rq = fg * 4;
  float bias[4];
#pragma unroll
  for (int nb = 0; nb < 4; ++nb)
    bias[nb] = (kc == 0) ? b2[e * D_MODEL + n0 + wn + nb * 16 + fr] : 0.f;

#pragma unroll
  for (int mb = 0; mb < 8; ++mb)
#pragma unroll
    for (int r = 0; r < 4; ++r) {
      const int rowT = wm + mb * 16 + rq + r;
      if (m0 + rowT < cnt) {
        const int si = e * NTOK + m0 + rowT;
        const int tok = rowlist[si];
        const float g = gatelist[si];
        float* orow = out + (size_t)tok * D_MODEL;
#pragma unroll
        for (int nb = 0; nb < 4; ++nb) {
          const int col = n0 + wn + nb * 16 + fr;
          atomicAdd(&orow[col], g * (acc[mb][nb][r] + bias[nb]));
        }
      }
    }
}

// ---------------- launch ----------------
extern "C" void kernel_launch(void* const* d_in, const int* in_sizes, int n_in,
                              void* d_out, int out_size, void* d_ws, size_t ws_size,
                              hipStream_t stream) {
  const float* X  = (const float*)d_in[0];
  const float* Wr = (const float*)d_in[1];
  const float* br = (const float*)d_in[2];
  const float* W1 = (const float*)d_in[3];
  const float* b1 = (const float*)d_in[4];
  const float* W2 = (const float*)d_in[5];
  const float* b2 = (const float*)d_in[6];
  float* out = (float*)d_out;

  char* w = (char*)d_ws;
  int*   topIdx   = (int*)(w);                                   // 32 KB
  float* topGate  = (float*)(w + (32 << 10));                    // 32 KB
  int*   counts   = (int*)(w + (64 << 10));                      // 64 B
  int*   bankOff  = (int*)(w + (64 << 10) + 256);                // 68 B
  int*   rowlist  = (int*)(w + (66 << 10));                      // 256 KB
  float* gatelist = (float*)(w + (66 << 10) + NBANKS * NTOK * 4);// 256 KB
  unsigned short* Xb = (unsigned short*)(w + (1 << 20));         // 8 MiB
  unsigned short* H  = (unsigned short*)(w + (16 << 20));        // 64 MiB

  const size_t needed = (size_t)(16 << 20) + (size_t)(NTOK * 2) * D_HIDDEN * 2;
  if (ws_size < needed) return;

  zero_out_k<<<dim3(4096), dim3(256), 0, stream>>>((float4*)out, counts);
  cvtx_k<<<dim3(NTOK * D_MODEL / 8 / 256), dim3(256), 0, stream>>>(X, Xb);
  router_k<<<dim3(NTOK), dim3(64), 0, stream>>>(X, Wr, br, topIdx, topGate);
  build_lists_k<<<dim3(16), dim3(256), 0, stream>>>(topIdx, topGate, counts, rowlist, gatelist);
  scan_k<<<dim3(1), dim3(64), 0, stream>>>(counts, bankOff);
  gemm1_k<<<dim3(8192), dim3(256), 0, stream>>>(Xb, W1, b1, counts, bankOff, rowlist, H);
  gemm2_k<<<dim3(8192), dim3(256), 0, stream>>>(H, W2, b2, counts, bankOff, rowlist, gatelist, out);
}

// Round 12
// 607.427 us; speedup vs baseline: 1.0923x; 1.0923x over previous
//
#include <hip/hip_runtime.h>
#include <stdint.h>

#define D_MODEL   1024
#define D_HIDDEN  4096
#define NBANKS    16
#define NTOK      4096      // 4 * 1024 tokens

#define BM 128
#define BN 128
#define BK 32
#define TBUF (BM * BK)      // elems per LDS buffer (8 KB bf16)
#define KS2 4               // K-split for gemm2

typedef __attribute__((ext_vector_type(8))) short bf16x8;
typedef __attribute__((ext_vector_type(4))) float f32x4;
typedef __attribute__((ext_vector_type(4))) unsigned int u32x4;
typedef __attribute__((ext_vector_type(2))) unsigned int u32x2;

__device__ __forceinline__ unsigned short f2bf(float f) {
  unsigned u = __builtin_bit_cast(unsigned, f);
  u += 0x7FFFu + ((u >> 16) & 1u);
  return (unsigned short)(u >> 16);
}

__device__ __forceinline__ unsigned cvtpk(float lo, float hi) {
  unsigned r;
  asm("v_cvt_pk_bf16_f32 %0, %1, %2" : "=v"(r) : "v"(lo), "v"(hi));
  return r;
}

// async global->LDS, 16 B per lane; LDS dest = wave-uniform base + lane*16
__device__ __forceinline__ void glds16(const unsigned short* g, unsigned short* l) {
  __builtin_amdgcn_global_load_lds(
      (const __attribute__((address_space(1))) unsigned int*)(const void*)g,
      (__attribute__((address_space(3))) unsigned int*)(void*)l, 16, 0, 0);
}

// LDS elem index for [rows][32] bf16 tiles (64-B rows, 4x 16B chunks).
// chunk ^= (r>>1)&3  (r7-proven map; A-side now written by glds with the
// SOURCE pre-swizzled to land in this same layout).
__device__ __forceinline__ int sidx(int r, int k) {
  return (r << 5) + ((((k >> 3) ^ ((r >> 1) & 3)) << 3) | (k & 7));
}

// ---------------- zero output + counts ----------------
__global__ __launch_bounds__(256) void zero_out_k(float4* __restrict__ out4,
                                                  int* __restrict__ counts) {
  size_t i = (size_t)blockIdx.x * 256 + threadIdx.x;
  out4[i] = make_float4(0.f, 0.f, 0.f, 0.f);
  if (blockIdx.x == 0 && threadIdx.x < NBANKS) counts[threadIdx.x] = 0;
}

// ---------------- X f32 -> bf16 pre-convert ----------------
__global__ __launch_bounds__(256) void cvtx_k(const float* __restrict__ X,
                                              unsigned short* __restrict__ Xb) {
  const size_t i = ((size_t)blockIdx.x * 256 + threadIdx.x) * 8;
  const float4 a = *(const float4*)(X + i);
  const float4 b = *(const float4*)(X + i + 4);
  u32x4 v;
  v[0] = cvtpk(a.x, a.y); v[1] = cvtpk(a.z, a.w);
  v[2] = cvtpk(b.x, b.y); v[3] = cvtpk(b.z, b.w);
  *(u32x4*)(Xb + i) = v;
}

// ---------------- router ----------------
__global__ __launch_bounds__(64) void router_k(const float* __restrict__ x,
                                               const float* __restrict__ Wr,
                                               const float* __restrict__ br,
                                               int* __restrict__ topIdx,
                                               float* __restrict__ topGate) {
  const int t = blockIdx.x;
  const int l = threadIdx.x;
  const float* xr = x + (size_t)t * D_MODEL;

  float acc[NBANKS];
#pragma unroll
  for (int e = 0; e < NBANKS; ++e) acc[e] = 0.f;

  for (int d = l; d < D_MODEL; d += 64) {
    const float xv = xr[d];
    const float* wrow = Wr + (size_t)d * NBANKS;
#pragma unroll
    for (int e = 0; e < NBANKS; ++e) acc[e] += xv * wrow[e];
  }
#pragma unroll
  for (int e = 0; e < NBANKS; ++e) {
#pragma unroll
    for (int m = 1; m < 64; m <<= 1) acc[e] += __shfl_xor(acc[e], m, 64);
  }
#pragma unroll
  for (int e = 0; e < NBANKS; ++e) acc[e] += br[e];

  if (l == 0) {
    float mx = acc[0];
#pragma unroll
    for (int e = 1; e < NBANKS; ++e) mx = fmaxf(mx, acc[e]);
    float p[NBANKS];
    float s = 0.f;
#pragma unroll
    for (int e = 0; e < NBANKS; ++e) { p[e] = expf(acc[e] - mx); s += p[e]; }
    int i0 = 0; float v0 = p[0];
#pragma unroll
    for (int e = 1; e < NBANKS; ++e) if (p[e] > v0) { v0 = p[e]; i0 = e; }
    int i1 = -1; float v1 = -1.f;
#pragma unroll
    for (int e = 0; e < NBANKS; ++e) if (e != i0 && p[e] > v1) { v1 = p[e]; i1 = e; }
    const float inv = 1.f / s;
    topIdx[2 * t]     = i0;
    topIdx[2 * t + 1] = i1;
    topGate[2 * t]     = v0 * inv;
    topGate[2 * t + 1] = v1 * inv;
  }
}

// ---------------- build per-bank token lists ----------------
__global__ __launch_bounds__(256) void build_lists_k(const int* __restrict__ topIdx,
                                                     const float* __restrict__ topGate,
                                                     int* __restrict__ counts,
                                                     int* __restrict__ rowlist,
                                                     float* __restrict__ gatelist) {
  const int t = blockIdx.x * 256 + threadIdx.x;
  if (t >= NTOK) return;
#pragma unroll
  for (int k = 0; k < 2; ++k) {
    const int e = topIdx[2 * t + k];
    const int p = atomicAdd(&counts[e], 1);
    rowlist[e * NTOK + p]  = t;
    gatelist[e * NTOK + p] = topGate[2 * t + k];
  }
}

__global__ void scan_k(const int* __restrict__ counts, int* __restrict__ bankOff) {
  if (threadIdx.x == 0) {
    int s = 0;
#pragma unroll
    for (int e = 0; e < NBANKS; ++e) { bankOff[e] = s; s += counts[e]; }
    bankOff[NBANKS] = s;
  }
}

// ---------------- GEMM1: H = relu(gather(Xb) @ W1[e] + b1[e]) ----------------
// r7 structure + XCD chunked swizzle + A staged via global_load_lds.
__global__ __launch_bounds__(256, 2) void gemm1_k(const unsigned short* __restrict__ Xb,
                                                  const float* __restrict__ W1,
                                                  const float* __restrict__ b1,
                                                  const int* __restrict__ counts,
                                                  const int* __restrict__ bankOff,
                                                  const int* __restrict__ rowlist,
                                                  unsigned short* __restrict__ H) {
  // nwg = 32m x 32n x 16e = 16384; chunked XCD swizzle (C = 2048), m-fastest
  const int orig = (blockIdx.x & 7) * 2048 + (blockIdx.x >> 3);
  const int mI = orig & 31;
  const int nI = (orig >> 5) & 31;
  const int e  = orig >> 10;

  const int cnt = counts[e];
  const int m0  = mI * BM;
  if (m0 >= cnt) return;
  const int n0  = nI * BN;

  const int tid  = threadIdx.x;
  const int lane = tid & 63;
  const int w    = tid >> 6;
  const int wm   = (w >> 1) * 64;
  const int wn   = (w & 1) * 64;
  const int fr   = lane & 15;
  const int fg   = lane >> 4;

  __shared__ unsigned short Xs[2 * TBUF];
  __shared__ unsigned short Ws[2 * TBUF];

  // A staging via glds: wave w covers chunks q=2w+c (16 rows x 64 B each).
  // Lane l -> row = 16q + (l>>2), slot s = l&3 holds k-chunk s ^ ((row>>1)&3).
  const unsigned short* agp[2];
  int albase[2];
#pragma unroll
  for (int c = 0; c < 2; ++c) {
    const int q   = 2 * w + c;
    const int row = 16 * q + (lane >> 2);
    const int gi  = min(m0 + row, cnt - 1);
    const int tok = rowlist[e * NTOK + gi];
    const int kc_ = (lane & 3) ^ ((row >> 1) & 3);
    agp[c]    = Xb + (size_t)tok * D_MODEL + 8 * kc_;
    albase[c] = q * 512;          // elems; lane offset applied by HW (+16B/lane)
  }

  // B staging: 4n x 4k micro-transpose; n4 = 4*(tid&31), k4 = 4*(tid>>5)
  const int n4 = 4 * (tid & 31);
  const int k4 = 4 * (tid >> 5);
  const float* Bsrc = W1 + (size_t)e * D_MODEL * D_HIDDEN + (size_t)k4 * D_HIDDEN + n0 + n4;
  int wo[4];
#pragma unroll
  for (int i = 0; i < 4; ++i) wo[i] = sidx(n4 + i, k4);

  int aoff[4], boff[4];
#pragma unroll
  for (int i = 0; i < 4; ++i) {
    aoff[i] = sidx(wm + i * 16 + fr, fg * 8);
    boff[i] = sidx(wn + i * 16 + fr, fg * 8);
  }

  float rbf[4][4];

  f32x4 acc[4][4];
#pragma unroll
  for (int i = 0; i < 4; ++i)
#pragma unroll
    for (int j = 0; j < 4; ++j)
#pragma unroll
      for (int r = 0; r < 4; ++r) acc[i][j][r] = 0.f;

  unsigned short* xc = &Xs[0];       unsigned short* wc = &Ws[0];
  unsigned short* xn = &Xs[TBUF];    unsigned short* wn_ = &Ws[TBUF];

  auto GLDSA = [&](unsigned short* xs, int t) {
    glds16(agp[0] + t * BK, xs + albase[0]);
    glds16(agp[1] + t * BK, xs + albase[1]);
  };
  auto LOADB = [&](int t) {
    const float* bp = Bsrc + (size_t)t * BK * D_HIDDEN;
#pragma unroll
    for (int kk = 0; kk < 4; ++kk)
      *(float4*)&rbf[kk][0] = *(const float4*)(bp + (size_t)kk * D_HIDDEN);
  };
  auto WRITEB = [&](unsigned short* ws) {
#pragma unroll
    for (int i = 0; i < 4; ++i) {
      u32x2 v;
      v[0] = cvtpk(rbf[0][i], rbf[1][i]);
      v[1] = cvtpk(rbf[2][i], rbf[3][i]);
      *(u32x2*)(ws + wo[i]) = v;
    }
  };
  auto COMPUTE = [&](const unsigned short* xs, const unsigned short* ws) {
    bf16x8 af[4], bb[4];
#pragma unroll
    for (int mb = 0; mb < 4; ++mb) af[mb] = *(const bf16x8*)(xs + aoff[mb]);
#pragma unroll
    for (int nb = 0; nb < 4; ++nb) bb[nb] = *(const bf16x8*)(ws + boff[nb]);
    __builtin_amdgcn_s_setprio(1);
#pragma unroll
    for (int mb = 0; mb < 4; ++mb)
#pragma unroll
      for (int nb = 0; nb < 4; ++nb)
        acc[mb][nb] = __builtin_amdgcn_mfma_f32_16x16x32_bf16(af[mb], bb[nb], acc[mb][nb], 0, 0, 0);
    __builtin_amdgcn_s_setprio(0);
  };

  const int NT = D_MODEL / BK;   // 32
  GLDSA(xc, 0);
  LOADB(0);
  WRITEB(wc);
  __syncthreads();               // drains glds (vmcnt) + ds writes
#pragma unroll 1
  for (int t = 0; t < NT; ++t) {
    if (t + 1 < NT) { GLDSA(xn, t + 1); LOADB(t + 1); }
    __builtin_amdgcn_sched_barrier(0);   // keep load issue above compute
    COMPUTE(xc, wc);
    if (t + 1 < NT) WRITEB(wn_);
    __syncthreads();
    unsigned short* t0 = xc; xc = xn;  xn  = t0;
    unsigned short* t1 = wc; wc = wn_; wn_ = t1;
  }

  // epilogue: relu(acc + b1) -> H (bf16)
  const int hb = bankOff[e] + m0;
  const int rq = fg * 4;
#pragma unroll
  for (int nb = 0; nb < 4; ++nb) {
    const int col = n0 + wn + nb * 16 + fr;
    const float bias = b1[e * D_HIDDEN + col];
#pragma unroll
    for (int mb = 0; mb < 4; ++mb)
#pragma unroll
      for (int r = 0; r < 4; ++r) {
        const int rowT = wm + mb * 16 + rq + r;
        if (m0 + rowT < cnt) {
          float v = acc[mb][nb][r] + bias;
          v = fmaxf(v, 0.f);
          H[(size_t)(hb + rowT) * D_HIDDEN + col] = f2bf(v);
        }
      }
  }
}

// ---------------- GEMM2: out += gate * (H @ W2[e] + b2[e]), K-split x4 ----
__global__ __launch_bounds__(256, 2) void gemm2_k(const unsigned short* __restrict__ H,
                                                  const float* __restrict__ W2,
                                                  const float* __restrict__ b2,
                                                  const int* __restrict__ counts,
                                                  const int* __restrict__ bankOff,
                                                  const int* __restrict__ rowlist,
                                                  const float* __restrict__ gatelist,
                                                  float* __restrict__ out) {
  // nwg = 32m x 8n x 64(e,kc) = 16384; chunked XCD swizzle (C = 2048), m-fastest
  const int orig = (blockIdx.x & 7) * 2048 + (blockIdx.x >> 3);
  const int mI = orig & 31;
  const int nI = (orig >> 5) & 7;
  const int z  = orig >> 8;
  const int e  = z >> 2;
  const int kc = z & 3;

  const int cnt = counts[e];
  const int m0  = mI * BM;
  if (m0 >= cnt) return;
  const int n0  = nI * BN;
  const int kc0 = kc * (D_HIDDEN / KS2);   // 0, 1024, 2048, 3072

  const int tid  = threadIdx.x;
  const int lane = tid & 63;
  const int w    = tid >> 6;
  const int wm   = (w >> 1) * 64;
  const int wn   = (w & 1) * 64;
  const int fr   = lane & 15;
  const int fg   = lane >> 4;

  __shared__ unsigned short Xs[2 * TBUF];
  __shared__ unsigned short Ws[2 * TBUF];

  const int hb = bankOff[e];
  const unsigned short* agp[2];
  int albase[2];
#pragma unroll
  for (int c = 0; c < 2; ++c) {
    const int q   = 2 * w + c;
    const int row = 16 * q + (lane >> 2);
    const int gi  = hb + min(m0 + row, cnt - 1);
    const int kc_ = (lane & 3) ^ ((row >> 1) & 3);
    agp[c]    = H + (size_t)gi * D_HIDDEN + kc0 + 8 * kc_;
    albase[c] = q * 512;
  }

  const int n4 = 4 * (tid & 31);
  const int k4 = 4 * (tid >> 5);
  const float* Bsrc = W2 + (size_t)e * D_HIDDEN * D_MODEL + (size_t)(kc0 + k4) * D_MODEL + n0 + n4;
  int wo[4];
#pragma unroll
  for (int i = 0; i < 4; ++i) wo[i] = sidx(n4 + i, k4);

  int aoff[4], boff[4];
#pragma unroll
  for (int i = 0; i < 4; ++i) {
    aoff[i] = sidx(wm + i * 16 + fr, fg * 8);
    boff[i] = sidx(wn + i * 16 + fr, fg * 8);
  }

  float rbf[4][4];

  f32x4 acc[4][4];
#pragma unroll
  for (int i = 0; i < 4; ++i)
#pragma unroll
    for (int j = 0; j < 4; ++j)
#pragma unroll
      for (int r = 0; r < 4; ++r) acc[i][j][r] = 0.f;

  unsigned short* xc = &Xs[0];       unsigned short* wc = &Ws[0];
  unsigned short* xn = &Xs[TBUF];    unsigned short* wn_ = &Ws[TBUF];

  auto GLDSA = [&](unsigned short* xs, int t) {
    glds16(agp[0] + t * BK, xs + albase[0]);
    glds16(agp[1] + t * BK, xs + albase[1]);
  };
  auto LOADB = [&](int t) {
    const float* bp = Bsrc + (size_t)t * BK * D_MODEL;
#pragma unroll
    for (int kk = 0; kk < 4; ++kk)
      *(float4*)&rbf[kk][0] = *(const float4*)(bp + (size_t)kk * D_MODEL);
  };
  auto WRITEB = [&](unsigned short* ws) {
#pragma unroll
    for (int i = 0; i < 4; ++i) {
      u32x2 v;
      v[0] = cvtpk(rbf[0][i], rbf[1][i]);
      v[1] = cvtpk(rbf[2][i], rbf[3][i]);
      *(u32x2*)(ws + wo[i]) = v;
    }
  };
  auto COMPUTE = [&](const unsigned short* xs, const unsigned short* ws) {
    bf16x8 af[4], bb[4];
#pragma unroll
    for (int mb = 0; mb < 4; ++mb) af[mb] = *(const bf16x8*)(xs + aoff[mb]);
#pragma unroll
    for (int nb = 0; nb < 4; ++nb) bb[nb] = *(const bf16x8*)(ws + boff[nb]);
    __builtin_amdgcn_s_setprio(1);
#pragma unroll
    for (int mb = 0; mb < 4; ++mb)
#pragma unroll
      for (int nb = 0; nb < 4; ++nb)
        acc[mb][nb] = __builtin_amdgcn_mfma_f32_16x16x32_bf16(af[mb], bb[nb], acc[mb][nb], 0, 0, 0);
    __builtin_amdgcn_s_setprio(0);
  };

  const int NT = (D_HIDDEN / KS2) / BK;   // 32
  GLDSA(xc, 0);
  LOADB(0);
  WRITEB(wc);
  __syncthreads();
#pragma unroll 1
  for (int t = 0; t < NT; ++t) {
    if (t + 1 < NT) { GLDSA(xn, t + 1); LOADB(t + 1); }
    __builtin_amdgcn_sched_barrier(0);
    COMPUTE(xc, wc);
    if (t + 1 < NT) WRITEB(wn_);
    __syncthreads();
    unsigned short* t0 = xc; xc = xn;  xn  = t0;
    unsigned short* t1 = wc; wc = wn_; wn_ = t1;
  }

  // epilogue: out[tok] += gate * (acc [+ b2 if kc==0])
  const int rq = fg * 4;
  float bias[4];
#pragma unroll
  for (int nb = 0; nb < 4; ++nb)
    bias[nb] = (kc == 0) ? b2[e * D_MODEL + n0 + wn + nb * 16 + fr] : 0.f;

#pragma unroll
  for (int mb = 0; mb < 4; ++mb)
#pragma unroll
    for (int r = 0; r < 4; ++r) {
      const int rowT = wm + mb * 16 + rq + r;
      if (m0 + rowT < cnt) {
        const int si = e * NTOK + m0 + rowT;
        const int tok = rowlist[si];
        const float g = gatelist[si];
        float* orow = out + (size_t)tok * D_MODEL;
#pragma unroll
        for (int nb = 0; nb < 4; ++nb) {
          const int col = n0 + wn + nb * 16 + fr;
          atomicAdd(&orow[col], g * (acc[mb][nb][r] + bias[nb]));
        }
      }
    }
}

// ---------------- launch ----------------
extern "C" void kernel_launch(void* const* d_in, const int* in_sizes, int n_in,
                              void* d_out, int out_size, void* d_ws, size_t ws_size,
                              hipStream_t stream) {
  const float* X  = (const float*)d_in[0];
  const float* Wr = (const float*)d_in[1];
  const float* br = (const float*)d_in[2];
  const float* W1 = (const float*)d_in[3];
  const float* b1 = (const float*)d_in[4];
  const float* W2 = (const float*)d_in[5];
  const float* b2 = (const float*)d_in[6];
  float* out = (float*)d_out;

  char* w = (char*)d_ws;
  int*   topIdx   = (int*)(w);                                   // 32 KB
  float* topGate  = (float*)(w + (32 << 10));                    // 32 KB
  int*   counts   = (int*)(w + (64 << 10));                      // 64 B
  int*   bankOff  = (int*)(w + (64 << 10) + 256);                // 68 B
  int*   rowlist  = (int*)(w + (66 << 10));                      // 256 KB
  float* gatelist = (float*)(w + (66 << 10) + NBANKS * NTOK * 4);// 256 KB
  unsigned short* Xb = (unsigned short*)(w + (1 << 20));         // 8 MiB
  unsigned short* H  = (unsigned short*)(w + (16 << 20));        // 64 MiB

  const size_t needed = (size_t)(16 << 20) + (size_t)(NTOK * 2) * D_HIDDEN * 2;
  if (ws_size < needed) return;

  zero_out_k<<<dim3(4096), dim3(256), 0, stream>>>((float4*)out, counts);
  cvtx_k<<<dim3(NTOK * D_MODEL / 8 / 256), dim3(256), 0, stream>>>(X, Xb);
  router_k<<<dim3(NTOK), dim3(64), 0, stream>>>(X, Wr, br, topIdx, topGate);
  build_lists_k<<<dim3(16), dim3(256), 0, stream>>>(topIdx, topGate, counts, rowlist, gatelist);
  scan_k<<<dim3(1), dim3(64), 0, stream>>>(counts, bankOff);
  gemm1_k<<<dim3(16384), dim3(256), 0, stream>>>(Xb, W1, b1, counts, bankOff, rowlist, H);
  gemm2_k<<<dim3(16384), dim3(256), 0, stream>>>(H, W2, b2, counts, bankOff, rowlist, gatelist, out);
}

// Round 13
// 460.928 us; speedup vs baseline: 1.4394x; 1.3178x over previous
//
#include <hip/hip_runtime.h>
#include <stdint.h>

#define D_MODEL   1024
#define D_HIDDEN  4096
#define NBANKS    16
#define NTOK      4096      // 4 * 1024 tokens

#define BM 128
#define BN 128
#define BK 32
#define TBUF (BM * BK)      // elems per LDS buffer (8 KB bf16)
#define KS2 4               // K-split for gemm2
#define MAXT 512            // max live (e,m0) tiles (worst case)

typedef __attribute__((ext_vector_type(8))) short bf16x8;
typedef __attribute__((ext_vector_type(4))) float f32x4;
typedef __attribute__((ext_vector_type(4))) unsigned int u32x4;
typedef __attribute__((ext_vector_type(2))) unsigned int u32x2;

__device__ __forceinline__ unsigned short f2bf(float f) {
  unsigned u = __builtin_bit_cast(unsigned, f);
  u += 0x7FFFu + ((u >> 16) & 1u);
  return (unsigned short)(u >> 16);
}

__device__ __forceinline__ unsigned cvtpk(float lo, float hi) {
  unsigned r;
  asm("v_cvt_pk_bf16_f32 %0, %1, %2" : "=v"(r) : "v"(lo), "v"(hi));
  return r;
}

// LDS elem index for [rows][32] bf16 tiles (64-B rows, 4x 16B chunks).
// chunk ^= (r>>1)&3  (r7 map, best measured config).
__device__ __forceinline__ int sidx(int r, int k) {
  return (r << 5) + ((((k >> 3) ^ ((r >> 1) & 3)) << 3) | (k & 7));
}

// ---------------- zero output + counts ----------------
__global__ __launch_bounds__(256) void zero_out_k(float4* __restrict__ out4,
                                                  int* __restrict__ counts) {
  size_t i = (size_t)blockIdx.x * 256 + threadIdx.x;
  out4[i] = make_float4(0.f, 0.f, 0.f, 0.f);
  if (blockIdx.x == 0 && threadIdx.x < NBANKS) counts[threadIdx.x] = 0;
}

// ---------------- X f32 -> bf16 pre-convert ----------------
__global__ __launch_bounds__(256) void cvtx_k(const float* __restrict__ X,
                                              unsigned short* __restrict__ Xb) {
  const size_t i = ((size_t)blockIdx.x * 256 + threadIdx.x) * 8;
  const float4 a = *(const float4*)(X + i);
  const float4 b = *(const float4*)(X + i + 4);
  u32x4 v;
  v[0] = cvtpk(a.x, a.y); v[1] = cvtpk(a.z, a.w);
  v[2] = cvtpk(b.x, b.y); v[3] = cvtpk(b.z, b.w);
  *(u32x4*)(Xb + i) = v;
}

// ---------------- router ----------------
__global__ __launch_bounds__(64) void router_k(const float* __restrict__ x,
                                               const float* __restrict__ Wr,
                                               const float* __restrict__ br,
                                               int* __restrict__ topIdx,
                                               float* __restrict__ topGate) {
  const int t = blockIdx.x;
  const int l = threadIdx.x;
  const float* xr = x + (size_t)t * D_MODEL;

  float acc[NBANKS];
#pragma unroll
  for (int e = 0; e < NBANKS; ++e) acc[e] = 0.f;

  for (int d = l; d < D_MODEL; d += 64) {
    const float xv = xr[d];
    const float* wrow = Wr + (size_t)d * NBANKS;
#pragma unroll
    for (int e = 0; e < NBANKS; ++e) acc[e] += xv * wrow[e];
  }
#pragma unroll
  for (int e = 0; e < NBANKS; ++e) {
#pragma unroll
    for (int m = 1; m < 64; m <<= 1) acc[e] += __shfl_xor(acc[e], m, 64);
  }
#pragma unroll
  for (int e = 0; e < NBANKS; ++e) acc[e] += br[e];

  if (l == 0) {
    float mx = acc[0];
#pragma unroll
    for (int e = 1; e < NBANKS; ++e) mx = fmaxf(mx, acc[e]);
    float p[NBANKS];
    float s = 0.f;
#pragma unroll
    for (int e = 0; e < NBANKS; ++e) { p[e] = expf(acc[e] - mx); s += p[e]; }
    int i0 = 0; float v0 = p[0];
#pragma unroll
    for (int e = 1; e < NBANKS; ++e) if (p[e] > v0) { v0 = p[e]; i0 = e; }
    int i1 = -1; float v1 = -1.f;
#pragma unroll
    for (int e = 0; e < NBANKS; ++e) if (e != i0 && p[e] > v1) { v1 = p[e]; i1 = e; }
    const float inv = 1.f / s;
    topIdx[2 * t]     = i0;
    topIdx[2 * t + 1] = i1;
    topGate[2 * t]     = v0 * inv;
    topGate[2 * t + 1] = v1 * inv;
  }
}

// ---------------- build per-bank token lists ----------------
__global__ __launch_bounds__(256) void build_lists_k(const int* __restrict__ topIdx,
                                                     const float* __restrict__ topGate,
                                                     int* __restrict__ counts,
                                                     int* __restrict__ rowlist,
                                                     float* __restrict__ gatelist) {
  const int t = blockIdx.x * 256 + threadIdx.x;
  if (t >= NTOK) return;
#pragma unroll
  for (int k = 0; k < 2; ++k) {
    const int e = topIdx[2 * t + k];
    const int p = atomicAdd(&counts[e], 1);
    rowlist[e * NTOK + p]  = t;
    gatelist[e * NTOK + p] = topGate[2 * t + k];
  }
}

// scan + build compacted live-tile list (e, m0) so live blocks dispatch first
__global__ void scan_k(const int* __restrict__ counts, int* __restrict__ bankOff,
                       int* __restrict__ tileE, int* __restrict__ tileM,
                       int* __restrict__ nT) {
  if (threadIdx.x == 0) {
    int s = 0;
    int t = 0;
    for (int e = 0; e < NBANKS; ++e) {
      bankOff[e] = s;
      const int c = counts[e];
      s += c;
      for (int m = 0; m < c; m += BM) {
        tileE[t] = e;
        tileM[t] = m;
        ++t;
      }
    }
    bankOff[NBANKS] = s;
    nT[0] = t;
  }
}

// ---------------- GEMM1: H = relu(gather(Xb) @ W1[e] + b1[e]) ----------------
// r7 structure; grid.y = compacted live tile index (live blocks dispatch first).
__global__ __launch_bounds__(256, 2) void gemm1_k(const unsigned short* __restrict__ Xb,
                                                  const float* __restrict__ W1,
                                                  const float* __restrict__ b1,
                                                  const int* __restrict__ counts,
                                                  const int* __restrict__ bankOff,
                                                  const int* __restrict__ rowlist,
                                                  const int* __restrict__ tileE,
                                                  const int* __restrict__ tileM,
                                                  const int* __restrict__ nT,
                                                  unsigned short* __restrict__ H) {
  const int tI = blockIdx.y;
  if (tI >= nT[0]) return;
  const int e   = tileE[tI];
  const int m0  = tileM[tI];
  const int cnt = counts[e];
  const int n0  = blockIdx.x * BN;

  const int tid  = threadIdx.x;
  const int lane = tid & 63;
  const int w    = tid >> 6;
  const int wm   = (w >> 1) * 64;
  const int wn   = (w & 1) * 64;

  __shared__ unsigned short Xs[2 * TBUF];
  __shared__ unsigned short Ws[2 * TBUF];

  // A staging: row = tid>>1, 16 bf16 at ak
  const int arow = tid >> 1;
  const int ak   = (tid & 1) * 16;
  const int gi   = min(m0 + arow, cnt - 1);
  const int tok  = rowlist[e * NTOK + gi];
  const unsigned short* Asrc = Xb + (size_t)tok * D_MODEL + ak;
  const int xo0 = sidx(arow, ak);
  const int xo1 = sidx(arow, ak + 8);

  // B staging: 4n x 4k micro-transpose; n4 = 4*(tid&31), k4 = 4*(tid>>5)
  const int n4 = 4 * (tid & 31);
  const int k4 = 4 * (tid >> 5);
  const float* Bsrc = W1 + (size_t)e * D_MODEL * D_HIDDEN + (size_t)k4 * D_HIDDEN + n0 + n4;
  int wo[4];
#pragma unroll
  for (int i = 0; i < 4; ++i) wo[i] = sidx(n4 + i, k4);

  const int fr = lane & 15;
  const int fc = (lane >> 4) * 8;
  int aoff[4], boff[4];
#pragma unroll
  for (int i = 0; i < 4; ++i) {
    aoff[i] = sidx(wm + i * 16 + fr, fc);
    boff[i] = sidx(wn + i * 16 + fr, fc);
  }

  bf16x8 ra0, ra1;
  float rbf[4][4];

  f32x4 acc[4][4];
#pragma unroll
  for (int i = 0; i < 4; ++i)
#pragma unroll
    for (int j = 0; j < 4; ++j)
#pragma unroll
      for (int r = 0; r < 4; ++r) acc[i][j][r] = 0.f;

  unsigned short* xc = &Xs[0];       unsigned short* wc = &Ws[0];
  unsigned short* xn = &Xs[TBUF];    unsigned short* wn_ = &Ws[TBUF];

  auto LOAD = [&](int t) {
    const unsigned short* ap = Asrc + t * BK;
    ra0 = *(const bf16x8*)(ap);
    ra1 = *(const bf16x8*)(ap + 8);
    const float* bp = Bsrc + (size_t)t * BK * D_HIDDEN;
#pragma unroll
    for (int kk = 0; kk < 4; ++kk)
      *(float4*)&rbf[kk][0] = *(const float4*)(bp + (size_t)kk * D_HIDDEN);
  };

  auto WRITE = [&](unsigned short* xs, unsigned short* ws) {
    *(bf16x8*)(xs + xo0) = ra0;
    *(bf16x8*)(xs + xo1) = ra1;
#pragma unroll
    for (int i = 0; i < 4; ++i) {
      u32x2 v;
      v[0] = cvtpk(rbf[0][i], rbf[1][i]);
      v[1] = cvtpk(rbf[2][i], rbf[3][i]);
      *(u32x2*)(ws + wo[i]) = v;
    }
  };

  auto COMPUTE = [&](const unsigned short* xs, const unsigned short* ws) {
    bf16x8 af[4], bb[4];
#pragma unroll
    for (int mb = 0; mb < 4; ++mb) af[mb] = *(const bf16x8*)(xs + aoff[mb]);
#pragma unroll
    for (int nb = 0; nb < 4; ++nb) bb[nb] = *(const bf16x8*)(ws + boff[nb]);
#pragma unroll
    for (int mb = 0; mb < 4; ++mb)
#pragma unroll
      for (int nb = 0; nb < 4; ++nb)
        acc[mb][nb] = __builtin_amdgcn_mfma_f32_16x16x32_bf16(af[mb], bb[nb], acc[mb][nb], 0, 0, 0);
  };

  const int NT = D_MODEL / BK;   // 32
  LOAD(0);
  WRITE(xc, wc);
  __syncthreads();
#pragma unroll 1
  for (int t = 0; t < NT; ++t) {
    if (t + 1 < NT) LOAD(t + 1);
    __builtin_amdgcn_sched_barrier(0);   // keep loads above compute
    COMPUTE(xc, wc);
    if (t + 1 < NT) WRITE(xn, wn_);
    __syncthreads();
    unsigned short* t0 = xc; xc = xn;  xn  = t0;
    unsigned short* t1 = wc; wc = wn_; wn_ = t1;
  }

  // epilogue: relu(acc + b1) -> H (bf16)
  const int hb = bankOff[e] + m0;
  const int rq = (lane >> 4) * 4;
#pragma unroll
  for (int nb = 0; nb < 4; ++nb) {
    const int col = n0 + wn + nb * 16 + fr;
    const float bias = b1[e * D_HIDDEN + col];
#pragma unroll
    for (int mb = 0; mb < 4; ++mb)
#pragma unroll
      for (int r = 0; r < 4; ++r) {
        const int rowT = wm + mb * 16 + rq + r;
        if (m0 + rowT < cnt) {
          float v = acc[mb][nb][r] + bias;
          v = fmaxf(v, 0.f);
          H[(size_t)(hb + rowT) * D_HIDDEN + col] = f2bf(v);
        }
      }
  }
}

// ---------------- GEMM2: out += gate * (H @ W2[e] + b2[e]), K-split x4 ----
// grid.y = 4*tI + kc (live tiles first).
__global__ __launch_bounds__(256, 2) void gemm2_k(const unsigned short* __restrict__ H,
                                                  const float* __restrict__ W2,
                                                  const float* __restrict__ b2,
                                                  const int* __restrict__ counts,
                                                  const int* __restrict__ bankOff,
                                                  const int* __restrict__ rowlist,
                                                  const float* __restrict__ gatelist,
                                                  const int* __restrict__ tileE,
                                                  const int* __restrict__ tileM,
                                                  const int* __restrict__ nT,
                                                  float* __restrict__ out) {
  const int tI = blockIdx.y >> 2;
  const int kc = blockIdx.y & 3;
  if (tI >= nT[0]) return;
  const int e   = tileE[tI];
  const int m0  = tileM[tI];
  const int cnt = counts[e];
  const int n0  = blockIdx.x * BN;
  const int kc0 = kc * (D_HIDDEN / KS2);   // 0, 1024, 2048, 3072

  const int tid  = threadIdx.x;
  const int lane = tid & 63;
  const int w    = tid >> 6;
  const int wm   = (w >> 1) * 64;
  const int wn   = (w & 1) * 64;

  __shared__ unsigned short Xs[2 * TBUF];
  __shared__ unsigned short Ws[2 * TBUF];

  const int arow = tid >> 1;
  const int ak   = (tid & 1) * 16;
  const int hb   = bankOff[e];
  const int gi   = hb + min(m0 + arow, cnt - 1);
  const unsigned short* Asrc = H + (size_t)gi * D_HIDDEN + kc0 + ak;
  const int xo0 = sidx(arow, ak);
  const int xo1 = sidx(arow, ak + 8);

  const int n4 = 4 * (tid & 31);
  const int k4 = 4 * (tid >> 5);
  const float* Bsrc = W2 + (size_t)e * D_HIDDEN * D_MODEL + (size_t)(kc0 + k4) * D_MODEL + n0 + n4;
  int wo[4];
#pragma unroll
  for (int i = 0; i < 4; ++i) wo[i] = sidx(n4 + i, k4);

  const int fr = lane & 15;
  const int fc = (lane >> 4) * 8;
  int aoff[4], boff[4];
#pragma unroll
  for (int i = 0; i < 4; ++i) {
    aoff[i] = sidx(wm + i * 16 + fr, fc);
    boff[i] = sidx(wn + i * 16 + fr, fc);
  }

  bf16x8 ra0, ra1;
  float rbf[4][4];

  f32x4 acc[4][4];
#pragma unroll
  for (int i = 0; i < 4; ++i)
#pragma unroll
    for (int j = 0; j < 4; ++j)
#pragma unroll
      for (int r = 0; r < 4; ++r) acc[i][j][r] = 0.f;

  unsigned short* xc = &Xs[0];       unsigned short* wc = &Ws[0];
  unsigned short* xn = &Xs[TBUF];    unsigned short* wn_ = &Ws[TBUF];

  auto LOAD = [&](int t) {
    const unsigned short* ap = Asrc + t * BK;
    ra0 = *(const bf16x8*)(ap);
    ra1 = *(const bf16x8*)(ap + 8);
    const float* bp = Bsrc + (size_t)t * BK * D_MODEL;
#pragma unroll
    for (int kk = 0; kk < 4; ++kk)
      *(float4*)&rbf[kk][0] = *(const float4*)(bp + (size_t)kk * D_MODEL);
  };

  auto WRITE = [&](unsigned short* xs, unsigned short* ws) {
    *(bf16x8*)(xs + xo0) = ra0;
    *(bf16x8*)(xs + xo1) = ra1;
#pragma unroll
    for (int i = 0; i < 4; ++i) {
      u32x2 v;
      v[0] = cvtpk(rbf[0][i], rbf[1][i]);
      v[1] = cvtpk(rbf[2][i], rbf[3][i]);
      *(u32x2*)(ws + wo[i]) = v;
    }
  };

  auto COMPUTE = [&](const unsigned short* xs, const unsigned short* ws) {
    bf16x8 af[4], bb[4];
#pragma unroll
    for (int mb = 0; mb < 4; ++mb) af[mb] = *(const bf16x8*)(xs + aoff[mb]);
#pragma unroll
    for (int nb = 0; nb < 4; ++nb) bb[nb] = *(const bf16x8*)(ws + boff[nb]);
#pragma unroll
    for (int mb = 0; mb < 4; ++mb)
#pragma unroll
      for (int nb = 0; nb < 4; ++nb)
        acc[mb][nb] = __builtin_amdgcn_mfma_f32_16x16x32_bf16(af[mb], bb[nb], acc[mb][nb], 0, 0, 0);
  };

  const int NT = (D_HIDDEN / KS2) / BK;   // 32
  LOAD(0);
  WRITE(xc, wc);
  __syncthreads();
#pragma unroll 1
  for (int t = 0; t < NT; ++t) {
    if (t + 1 < NT) LOAD(t + 1);
    __builtin_amdgcn_sched_barrier(0);
    COMPUTE(xc, wc);
    if (t + 1 < NT) WRITE(xn, wn_);
    __syncthreads();
    unsigned short* t0 = xc; xc = xn;  xn  = t0;
    unsigned short* t1 = wc; wc = wn_; wn_ = t1;
  }

  // epilogue: out[tok] += gate * (acc [+ b2 if kc==0])
  const int rq = (lane >> 4) * 4;
  float bias[4];
#pragma unroll
  for (int nb = 0; nb < 4; ++nb)
    bias[nb] = (kc == 0) ? b2[e * D_MODEL + n0 + wn + nb * 16 + fr] : 0.f;

#pragma unroll
  for (int mb = 0; mb < 4; ++mb)
#pragma unroll
    for (int r = 0; r < 4; ++r) {
      const int rowT = wm + mb * 16 + rq + r;
      if (m0 + rowT < cnt) {
        const int si = e * NTOK + m0 + rowT;
        const int tok = rowlist[si];
        const float g = gatelist[si];
        float* orow = out + (size_t)tok * D_MODEL;
#pragma unroll
        for (int nb = 0; nb < 4; ++nb) {
          const int col = n0 + wn + nb * 16 + fr;
          atomicAdd(&orow[col], g * (acc[mb][nb][r] + bias[nb]));
        }
      }
    }
}

// ---------------- launch ----------------
extern "C" void kernel_launch(void* const* d_in, const int* in_sizes, int n_in,
                              void* d_out, int out_size, void* d_ws, size_t ws_size,
                              hipStream_t stream) {
  const float* X  = (const float*)d_in[0];
  const float* Wr = (const float*)d_in[1];
  const float* br = (const float*)d_in[2];
  const float* W1 = (const float*)d_in[3];
  const float* b1 = (const float*)d_in[4];
  const float* W2 = (const float*)d_in[5];
  const float* b2 = (const float*)d_in[6];
  float* out = (float*)d_out;

  char* w = (char*)d_ws;
  int*   topIdx   = (int*)(w);                                   // 32 KB
  float* topGate  = (float*)(w + (32 << 10));                    // 32 KB
  int*   counts   = (int*)(w + (64 << 10));                      // 64 B
  int*   bankOff  = (int*)(w + (64 << 10) + 256);                // 68 B
  int*   rowlist  = (int*)(w + (66 << 10));                      // 256 KB
  float* gatelist = (float*)(w + (66 << 10) + NBANKS * NTOK * 4);// 256 KB
  int*   tileE    = (int*)(w + (600 << 10));                     // 2 KB
  int*   tileM    = (int*)(w + (604 << 10));                     // 2 KB
  int*   nT       = (int*)(w + (608 << 10));                     // 4 B
  unsigned short* Xb = (unsigned short*)(w + (1 << 20));         // 8 MiB
  unsigned short* H  = (unsigned short*)(w + (16 << 20));        // 64 MiB

  const size_t needed = (size_t)(16 << 20) + (size_t)(NTOK * 2) * D_HIDDEN * 2;
  if (ws_size < needed) return;

  zero_out_k<<<dim3(4096), dim3(256), 0, stream>>>((float4*)out, counts);
  cvtx_k<<<dim3(NTOK * D_MODEL / 8 / 256), dim3(256), 0, stream>>>(X, Xb);
  router_k<<<dim3(NTOK), dim3(64), 0, stream>>>(X, Wr, br, topIdx, topGate);
  build_lists_k<<<dim3(16), dim3(256), 0, stream>>>(topIdx, topGate, counts, rowlist, gatelist);
  scan_k<<<dim3(1), dim3(64), 0, stream>>>(counts, bankOff, tileE, tileM, nT);
  gemm1_k<<<dim3(D_HIDDEN / BN, MAXT), dim3(256), 0, stream>>>(
      Xb, W1, b1, counts, bankOff, rowlist, tileE, tileM, nT, H);
  gemm2_k<<<dim3(D_MODEL / BN, MAXT * KS2), dim3(256), 0, stream>>>(
      H, W2, b2, counts, bankOff, rowlist, gatelist, tileE, tileM, nT, out);
}

// Round 14
// 451.867 us; speedup vs baseline: 1.4683x; 1.0201x over previous
//
#include <hip/hip_runtime.h>
#include <stdint.h>

#define D_MODEL   1024
#define D_HIDDEN  4096
#define NBANKS    16
#define NTOK      4096      // 4 * 1024 tokens

#define BM 128
#define BN 128
#define BK 32
#define TBUF (BM * BK)      // elems per LDS buffer (8 KB bf16)
#define KS2 4               // K-split for gemm2
#define MAXT 512            // max live (e,m0) tiles (worst case)

typedef __attribute__((ext_vector_type(8))) short bf16x8;
typedef __attribute__((ext_vector_type(4))) float f32x4;
typedef __attribute__((ext_vector_type(4))) unsigned int u32x4;
typedef __attribute__((ext_vector_type(2))) unsigned int u32x2;

__device__ __forceinline__ unsigned short f2bf(float f) {
  unsigned u = __builtin_bit_cast(unsigned, f);
  u += 0x7FFFu + ((u >> 16) & 1u);
  return (unsigned short)(u >> 16);
}

__device__ __forceinline__ unsigned cvtpk(float lo, float hi) {
  unsigned r;
  asm("v_cvt_pk_bf16_f32 %0, %1, %2" : "=v"(r) : "v"(lo), "v"(hi));
  return r;
}

// LDS elem index for [rows][32] bf16 tiles (64-B rows, 4x 16B chunks).
// chunk ^= (r>>1)&3  (r7 map, best measured config).
__device__ __forceinline__ int sidx(int r, int k) {
  return (r << 5) + ((((k >> 3) ^ ((r >> 1) & 3)) << 3) | (k & 7));
}

// ---------------- zero output + counts ----------------
__global__ __launch_bounds__(256) void zero_out_k(float4* __restrict__ out4,
                                                  int* __restrict__ counts) {
  size_t i = (size_t)blockIdx.x * 256 + threadIdx.x;
  out4[i] = make_float4(0.f, 0.f, 0.f, 0.f);
  if (blockIdx.x == 0 && threadIdx.x < NBANKS) counts[threadIdx.x] = 0;
}

// ---------------- X f32 -> bf16 pre-convert ----------------
__global__ __launch_bounds__(256) void cvtx_k(const float* __restrict__ X,
                                              unsigned short* __restrict__ Xb) {
  const size_t i = ((size_t)blockIdx.x * 256 + threadIdx.x) * 8;
  const float4 a = *(const float4*)(X + i);
  const float4 b = *(const float4*)(X + i + 4);
  u32x4 v;
  v[0] = cvtpk(a.x, a.y); v[1] = cvtpk(a.z, a.w);
  v[2] = cvtpk(b.x, b.y); v[3] = cvtpk(b.z, b.w);
  *(u32x4*)(Xb + i) = v;
}

// ---------------- router ----------------
__global__ __launch_bounds__(64) void router_k(const float* __restrict__ x,
                                               const float* __restrict__ Wr,
                                               const float* __restrict__ br,
                                               int* __restrict__ topIdx,
                                               float* __restrict__ topGate) {
  const int t = blockIdx.x;
  const int l = threadIdx.x;
  const float* xr = x + (size_t)t * D_MODEL;

  float acc[NBANKS];
#pragma unroll
  for (int e = 0; e < NBANKS; ++e) acc[e] = 0.f;

  for (int d = l; d < D_MODEL; d += 64) {
    const float xv = xr[d];
    const float* wrow = Wr + (size_t)d * NBANKS;
#pragma unroll
    for (int e = 0; e < NBANKS; ++e) acc[e] += xv * wrow[e];
  }
#pragma unroll
  for (int e = 0; e < NBANKS; ++e) {
#pragma unroll
    for (int m = 1; m < 64; m <<= 1) acc[e] += __shfl_xor(acc[e], m, 64);
  }
#pragma unroll
  for (int e = 0; e < NBANKS; ++e) acc[e] += br[e];

  if (l == 0) {
    float mx = acc[0];
#pragma unroll
    for (int e = 1; e < NBANKS; ++e) mx = fmaxf(mx, acc[e]);
    float p[NBANKS];
    float s = 0.f;
#pragma unroll
    for (int e = 0; e < NBANKS; ++e) { p[e] = expf(acc[e] - mx); s += p[e]; }
    int i0 = 0; float v0 = p[0];
#pragma unroll
    for (int e = 1; e < NBANKS; ++e) if (p[e] > v0) { v0 = p[e]; i0 = e; }
    int i1 = -1; float v1 = -1.f;
#pragma unroll
    for (int e = 0; e < NBANKS; ++e) if (e != i0 && p[e] > v1) { v1 = p[e]; i1 = e; }
    const float inv = 1.f / s;
    topIdx[2 * t]     = i0;
    topIdx[2 * t + 1] = i1;
    topGate[2 * t]     = v0 * inv;
    topGate[2 * t + 1] = v1 * inv;
  }
}

// ---------------- build per-bank token lists ----------------
__global__ __launch_bounds__(256) void build_lists_k(const int* __restrict__ topIdx,
                                                     const float* __restrict__ topGate,
                                                     int* __restrict__ counts,
                                                     int* __restrict__ rowlist,
                                                     float* __restrict__ gatelist) {
  const int t = blockIdx.x * 256 + threadIdx.x;
  if (t >= NTOK) return;
#pragma unroll
  for (int k = 0; k < 2; ++k) {
    const int e = topIdx[2 * t + k];
    const int p = atomicAdd(&counts[e], 1);
    rowlist[e * NTOK + p]  = t;
    gatelist[e * NTOK + p] = topGate[2 * t + k];
  }
}

// scan + build compacted live-tile list (e, m0) so live blocks dispatch first
__global__ void scan_k(const int* __restrict__ counts, int* __restrict__ bankOff,
                       int* __restrict__ tileE, int* __restrict__ tileM,
                       int* __restrict__ nT) {
  if (threadIdx.x == 0) {
    int s = 0;
    int t = 0;
    for (int e = 0; e < NBANKS; ++e) {
      bankOff[e] = s;
      const int c = counts[e];
      s += c;
      for (int m = 0; m < c; m += BM) {
        tileE[t] = e;
        tileM[t] = m;
        ++t;
      }
    }
    bankOff[NBANKS] = s;
    nT[0] = t;
  }
}

// ---------------- GEMM1: H = relu(gather(Xb) @ W1[e] + b1[e]) ----------------
// r13 structure + depth-2 register prefetch (P/Q sets, loop unrolled x2).
__global__ __launch_bounds__(256, 2) void gemm1_k(const unsigned short* __restrict__ Xb,
                                                  const float* __restrict__ W1,
                                                  const float* __restrict__ b1,
                                                  const int* __restrict__ counts,
                                                  const int* __restrict__ bankOff,
                                                  const int* __restrict__ rowlist,
                                                  const int* __restrict__ tileE,
                                                  const int* __restrict__ tileM,
                                                  const int* __restrict__ nT,
                                                  unsigned short* __restrict__ H) {
  const int tI = blockIdx.y;
  if (tI >= nT[0]) return;
  const int e   = tileE[tI];
  const int m0  = tileM[tI];
  const int cnt = counts[e];
  const int n0  = blockIdx.x * BN;

  const int tid  = threadIdx.x;
  const int lane = tid & 63;
  const int w    = tid >> 6;
  const int wm   = (w >> 1) * 64;
  const int wn   = (w & 1) * 64;

  __shared__ unsigned short Xs[2 * TBUF];
  __shared__ unsigned short Ws[2 * TBUF];

  // A staging: row = tid>>1, 16 bf16 at ak
  const int arow = tid >> 1;
  const int ak   = (tid & 1) * 16;
  const int gi   = min(m0 + arow, cnt - 1);
  const int tok  = rowlist[e * NTOK + gi];
  const unsigned short* Asrc = Xb + (size_t)tok * D_MODEL + ak;
  const int xo0 = sidx(arow, ak);
  const int xo1 = sidx(arow, ak + 8);

  // B staging: 4n x 4k micro-transpose; n4 = 4*(tid&31), k4 = 4*(tid>>5)
  const int n4 = 4 * (tid & 31);
  const int k4 = 4 * (tid >> 5);
  const float* Bsrc = W1 + (size_t)e * D_MODEL * D_HIDDEN + (size_t)k4 * D_HIDDEN + n0 + n4;
  int wo[4];
#pragma unroll
  for (int i = 0; i < 4; ++i) wo[i] = sidx(n4 + i, k4);

  const int fr = lane & 15;
  const int fc = (lane >> 4) * 8;
  int aoff[4], boff[4];
#pragma unroll
  for (int i = 0; i < 4; ++i) {
    aoff[i] = sidx(wm + i * 16 + fr, fc);
    boff[i] = sidx(wn + i * 16 + fr, fc);
  }

  // two independent in-flight register sets (rule #20: named, static)
  bf16x8 pa0, pa1, qa0, qa1;
  float pb[4][4], qb[4][4];

  f32x4 acc[4][4];
#pragma unroll
  for (int i = 0; i < 4; ++i)
#pragma unroll
    for (int j = 0; j < 4; ++j)
#pragma unroll
      for (int r = 0; r < 4; ++r) acc[i][j][r] = 0.f;

  unsigned short* xc = &Xs[0];       unsigned short* wc = &Ws[0];   // even tiles
  unsigned short* xn = &Xs[TBUF];    unsigned short* wn_ = &Ws[TBUF]; // odd tiles

  auto LOADP = [&](int t) {
    const unsigned short* ap = Asrc + t * BK;
    pa0 = *(const bf16x8*)(ap);
    pa1 = *(const bf16x8*)(ap + 8);
    const float* bp = Bsrc + (size_t)t * BK * D_HIDDEN;
#pragma unroll
    for (int kk = 0; kk < 4; ++kk)
      *(float4*)&pb[kk][0] = *(const float4*)(bp + (size_t)kk * D_HIDDEN);
  };
  auto LOADQ = [&](int t) {
    const unsigned short* ap = Asrc + t * BK;
    qa0 = *(const bf16x8*)(ap);
    qa1 = *(const bf16x8*)(ap + 8);
    const float* bp = Bsrc + (size_t)t * BK * D_HIDDEN;
#pragma unroll
    for (int kk = 0; kk < 4; ++kk)
      *(float4*)&qb[kk][0] = *(const float4*)(bp + (size_t)kk * D_HIDDEN);
  };
  auto WRITEP = [&](unsigned short* xs, unsigned short* ws) {
    *(bf16x8*)(xs + xo0) = pa0;
    *(bf16x8*)(xs + xo1) = pa1;
#pragma unroll
    for (int i = 0; i < 4; ++i) {
      u32x2 v;
      v[0] = cvtpk(pb[0][i], pb[1][i]);
      v[1] = cvtpk(pb[2][i], pb[3][i]);
      *(u32x2*)(ws + wo[i]) = v;
    }
  };
  auto WRITEQ = [&](unsigned short* xs, unsigned short* ws) {
    *(bf16x8*)(xs + xo0) = qa0;
    *(bf16x8*)(xs + xo1) = qa1;
#pragma unroll
    for (int i = 0; i < 4; ++i) {
      u32x2 v;
      v[0] = cvtpk(qb[0][i], qb[1][i]);
      v[1] = cvtpk(qb[2][i], qb[3][i]);
      *(u32x2*)(ws + wo[i]) = v;
    }
  };
  auto COMPUTE = [&](const unsigned short* xs, const unsigned short* ws) {
    bf16x8 af[4], bb[4];
#pragma unroll
    for (int mb = 0; mb < 4; ++mb) af[mb] = *(const bf16x8*)(xs + aoff[mb]);
#pragma unroll
    for (int nb = 0; nb < 4; ++nb) bb[nb] = *(const bf16x8*)(ws + boff[nb]);
#pragma unroll
    for (int mb = 0; mb < 4; ++mb)
#pragma unroll
      for (int nb = 0; nb < 4; ++nb)
        acc[mb][nb] = __builtin_amdgcn_mfma_f32_16x16x32_bf16(af[mb], bb[nb], acc[mb][nb], 0, 0, 0);
  };

  const int NT = D_MODEL / BK;   // 32 (even)
  LOADP(0);
  LOADQ(1);
  WRITEP(xc, wc);                // tile 0 -> buf0; P free
  __syncthreads();
#pragma unroll 1
  for (int t = 0; t < NT; t += 2) {
    if (t + 2 < NT) LOADP(t + 2);              // consumed at end of this iter
    __builtin_amdgcn_sched_barrier(0);
    COMPUTE(xc, wc);                           // tile t (buf0)
    WRITEQ(xn, wn_);                           // tile t+1 -> buf1; Q free
    __syncthreads();
    if (t + 3 < NT) LOADQ(t + 3);              // consumed next iter
    __builtin_amdgcn_sched_barrier(0);
    COMPUTE(xn, wn_);                          // tile t+1 (buf1)
    if (t + 2 < NT) WRITEP(xc, wc);            // tile t+2 -> buf0; P free
    __syncthreads();
  }

  // epilogue: relu(acc + b1) -> H (bf16)
  const int hb = bankOff[e] + m0;
  const int rq = (lane >> 4) * 4;
#pragma unroll
  for (int nb = 0; nb < 4; ++nb) {
    const int col = n0 + wn + nb * 16 + fr;
    const float bias = b1[e * D_HIDDEN + col];
#pragma unroll
    for (int mb = 0; mb < 4; ++mb)
#pragma unroll
      for (int r = 0; r < 4; ++r) {
        const int rowT = wm + mb * 16 + rq + r;
        if (m0 + rowT < cnt) {
          float v = acc[mb][nb][r] + bias;
          v = fmaxf(v, 0.f);
          H[(size_t)(hb + rowT) * D_HIDDEN + col] = f2bf(v);
        }
      }
  }
}

// ---------------- GEMM2: out += gate * (H @ W2[e] + b2[e]), K-split x4 ----
// grid.y = 4*tI + kc (live tiles first); depth-2 register prefetch.
__global__ __launch_bounds__(256, 2) void gemm2_k(const unsigned short* __restrict__ H,
                                                  const float* __restrict__ W2,
                                                  const float* __restrict__ b2,
                                                  const int* __restrict__ counts,
                                                  const int* __restrict__ bankOff,
                                                  const int* __restrict__ rowlist,
                                                  const float* __restrict__ gatelist,
                                                  const int* __restrict__ tileE,
                                                  const int* __restrict__ tileM,
                                                  const int* __restrict__ nT,
                                                  float* __restrict__ out) {
  const int tI = blockIdx.y >> 2;
  const int kc = blockIdx.y & 3;
  if (tI >= nT[0]) return;
  const int e   = tileE[tI];
  const int m0  = tileM[tI];
  const int cnt = counts[e];
  const int n0  = blockIdx.x * BN;
  const int kc0 = kc * (D_HIDDEN / KS2);   // 0, 1024, 2048, 3072

  const int tid  = threadIdx.x;
  const int lane = tid & 63;
  const int w    = tid >> 6;
  const int wm   = (w >> 1) * 64;
  const int wn   = (w & 1) * 64;

  __shared__ unsigned short Xs[2 * TBUF];
  __shared__ unsigned short Ws[2 * TBUF];

  const int arow = tid >> 1;
  const int ak   = (tid & 1) * 16;
  const int hb   = bankOff[e];
  const int gi   = hb + min(m0 + arow, cnt - 1);
  const unsigned short* Asrc = H + (size_t)gi * D_HIDDEN + kc0 + ak;
  const int xo0 = sidx(arow, ak);
  const int xo1 = sidx(arow, ak + 8);

  const int n4 = 4 * (tid & 31);
  const int k4 = 4 * (tid >> 5);
  const float* Bsrc = W2 + (size_t)e * D_HIDDEN * D_MODEL + (size_t)(kc0 + k4) * D_MODEL + n0 + n4;
  int wo[4];
#pragma unroll
  for (int i = 0; i < 4; ++i) wo[i] = sidx(n4 + i, k4);

  const int fr = lane & 15;
  const int fc = (lane >> 4) * 8;
  int aoff[4], boff[4];
#pragma unroll
  for (int i = 0; i < 4; ++i) {
    aoff[i] = sidx(wm + i * 16 + fr, fc);
    boff[i] = sidx(wn + i * 16 + fr, fc);
  }

  bf16x8 pa0, pa1, qa0, qa1;
  float pb[4][4], qb[4][4];

  f32x4 acc[4][4];
#pragma unroll
  for (int i = 0; i < 4; ++i)
#pragma unroll
    for (int j = 0; j < 4; ++j)
#pragma unroll
      for (int r = 0; r < 4; ++r) acc[i][j][r] = 0.f;

  unsigned short* xc = &Xs[0];       unsigned short* wc = &Ws[0];
  unsigned short* xn = &Xs[TBUF];    unsigned short* wn_ = &Ws[TBUF];

  auto LOADP = [&](int t) {
    const unsigned short* ap = Asrc + t * BK;
    pa0 = *(const bf16x8*)(ap);
    pa1 = *(const bf16x8*)(ap + 8);
    const float* bp = Bsrc + (size_t)t * BK * D_MODEL;
#pragma unroll
    for (int kk = 0; kk < 4; ++kk)
      *(float4*)&pb[kk][0] = *(const float4*)(bp + (size_t)kk * D_MODEL);
  };
  auto LOADQ = [&](int t) {
    const unsigned short* ap = Asrc + t * BK;
    qa0 = *(const bf16x8*)(ap);
    qa1 = *(const bf16x8*)(ap + 8);
    const float* bp = Bsrc + (size_t)t * BK * D_MODEL;
#pragma unroll
    for (int kk = 0; kk < 4; ++kk)
      *(float4*)&qb[kk][0] = *(const float4*)(bp + (size_t)kk * D_MODEL);
  };
  auto WRITEP = [&](unsigned short* xs, unsigned short* ws) {
    *(bf16x8*)(xs + xo0) = pa0;
    *(bf16x8*)(xs + xo1) = pa1;
#pragma unroll
    for (int i = 0; i < 4; ++i) {
      u32x2 v;
      v[0] = cvtpk(pb[0][i], pb[1][i]);
      v[1] = cvtpk(pb[2][i], pb[3][i]);
      *(u32x2*)(ws + wo[i]) = v;
    }
  };
  auto WRITEQ = [&](unsigned short* xs, unsigned short* ws) {
    *(bf16x8*)(xs + xo0) = qa0;
    *(bf16x8*)(xs + xo1) = qa1;
#pragma unroll
    for (int i = 0; i < 4; ++i) {
      u32x2 v;
      v[0] = cvtpk(qb[0][i], qb[1][i]);
      v[1] = cvtpk(qb[2][i], qb[3][i]);
      *(u32x2*)(ws + wo[i]) = v;
    }
  };
  auto COMPUTE = [&](const unsigned short* xs, const unsigned short* ws) {
    bf16x8 af[4], bb[4];
#pragma unroll
    for (int mb = 0; mb < 4; ++mb) af[mb] = *(const bf16x8*)(xs + aoff[mb]);
#pragma unroll
    for (int nb = 0; nb < 4; ++nb) bb[nb] = *(const bf16x8*)(ws + boff[nb]);
#pragma unroll
    for (int mb = 0; mb < 4; ++mb)
#pragma unroll
      for (int nb = 0; nb < 4; ++nb)
        acc[mb][nb] = __builtin_amdgcn_mfma_f32_16x16x32_bf16(af[mb], bb[nb], acc[mb][nb], 0, 0, 0);
  };

  const int NT = (D_HIDDEN / KS2) / BK;   // 32 (even)
  LOADP(0);
  LOADQ(1);
  WRITEP(xc, wc);
  __syncthreads();
#pragma unroll 1
  for (int t = 0; t < NT; t += 2) {
    if (t + 2 < NT) LOADP(t + 2);
    __builtin_amdgcn_sched_barrier(0);
    COMPUTE(xc, wc);
    WRITEQ(xn, wn_);
    __syncthreads();
    if (t + 3 < NT) LOADQ(t + 3);
    __builtin_amdgcn_sched_barrier(0);
    COMPUTE(xn, wn_);
    if (t + 2 < NT) WRITEP(xc, wc);
    __syncthreads();
  }

  // epilogue: out[tok] += gate * (acc [+ b2 if kc==0])
  const int rq = (lane >> 4) * 4;
  float bias[4];
#pragma unroll
  for (int nb = 0; nb < 4; ++nb)
    bias[nb] = (kc == 0) ? b2[e * D_MODEL + n0 + wn + nb * 16 + fr] : 0.f;

#pragma unroll
  for (int mb = 0; mb < 4; ++mb)
#pragma unroll
    for (int r = 0; r < 4; ++r) {
      const int rowT = wm + mb * 16 + rq + r;
      if (m0 + rowT < cnt) {
        const int si = e * NTOK + m0 + rowT;
        const int tok = rowlist[si];
        const float g = gatelist[si];
        float* orow = out + (size_t)tok * D_MODEL;
#pragma unroll
        for (int nb = 0; nb < 4; ++nb) {
          const int col = n0 + wn + nb * 16 + fr;
          atomicAdd(&orow[col], g * (acc[mb][nb][r] + bias[nb]));
        }
      }
    }
}

// ---------------- launch ----------------
extern "C" void kernel_launch(void* const* d_in, const int* in_sizes, int n_in,
                              void* d_out, int out_size, void* d_ws, size_t ws_size,
                              hipStream_t stream) {
  const float* X  = (const float*)d_in[0];
  const float* Wr = (const float*)d_in[1];
  const float* br = (const float*)d_in[2];
  const float* W1 = (const float*)d_in[3];
  const float* b1 = (const float*)d_in[4];
  const float* W2 = (const float*)d_in[5];
  const float* b2 = (const float*)d_in[6];
  float* out = (float*)d_out;

  char* w = (char*)d_ws;
  int*   topIdx   = (int*)(w);                                   // 32 KB
  float* topGate  = (float*)(w + (32 << 10));                    // 32 KB
  int*   counts   = (int*)(w + (64 << 10));                      // 64 B
  int*   bankOff  = (int*)(w + (64 << 10) + 256);                // 68 B
  int*   rowlist  = (int*)(w + (66 << 10));                      // 256 KB
  float* gatelist = (float*)(w + (66 << 10) + NBANKS * NTOK * 4);// 256 KB
  int*   tileE    = (int*)(w + (600 << 10));                     // 2 KB
  int*   tileM    = (int*)(w + (604 << 10));                     // 2 KB
  int*   nT       = (int*)(w + (608 << 10));                     // 4 B
  unsigned short* Xb = (unsigned short*)(w + (1 << 20));         // 8 MiB
  unsigned short* H  = (unsigned short*)(w + (16 << 20));        // 64 MiB

  const size_t needed = (size_t)(16 << 20) + (size_t)(NTOK * 2) * D_HIDDEN * 2;
  if (ws_size < needed) return;

  zero_out_k<<<dim3(4096), dim3(256), 0, stream>>>((float4*)out, counts);
  cvtx_k<<<dim3(NTOK * D_MODEL / 8 / 256), dim3(256), 0, stream>>>(X, Xb);
  router_k<<<dim3(NTOK), dim3(64), 0, stream>>>(X, Wr, br, topIdx, topGate);
  build_lists_k<<<dim3(16), dim3(256), 0, stream>>>(topIdx, topGate, counts, rowlist, gatelist);
  scan_k<<<dim3(1), dim3(64), 0, stream>>>(counts, bankOff, tileE, tileM, nT);
  gemm1_k<<<dim3(D_HIDDEN / BN, MAXT), dim3(256), 0, stream>>>(
      Xb, W1, b1, counts, bankOff, rowlist, tileE, tileM, nT, H);
  gemm2_k<<<dim3(D_MODEL / BN, MAXT * KS2), dim3(256), 0, stream>>>(
      H, W2, b2, counts, bankOff, rowlist, gatelist, tileE, tileM, nT, out);
}

// Round 15
// 447.768 us; speedup vs baseline: 1.4817x; 1.0092x over previous
//
#include <hip/hip_runtime.h>
#include <stdint.h>

#define D_MODEL   1024
#define D_HIDDEN  4096
#define NBANKS    16
#define NTOK      4096      // 4 * 1024 tokens

#define BM 128
#define BN 128
#define BK 32
#define TBUF (BM * BK)      // elems per LDS buffer (8 KB bf16)
#define KS2 4               // K-split for gemm2
#define MAXT 512            // max live (e,m0) tiles (worst case)

typedef __attribute__((ext_vector_type(8))) short bf16x8;
typedef __attribute__((ext_vector_type(4))) float f32x4;
typedef __attribute__((ext_vector_type(4))) unsigned int u32x4;
typedef __attribute__((ext_vector_type(2))) unsigned int u32x2;

__device__ __forceinline__ unsigned short f2bf(float f) {
  unsigned u = __builtin_bit_cast(unsigned, f);
  u += 0x7FFFu + ((u >> 16) & 1u);
  return (unsigned short)(u >> 16);
}

__device__ __forceinline__ unsigned cvtpk(float lo, float hi) {
  unsigned r;
  asm("v_cvt_pk_bf16_f32 %0, %1, %2" : "=v"(r) : "v"(lo), "v"(hi));
  return r;
}

// Barrier WITHOUT the vmcnt(0) drain __syncthreads would emit: LDS ops must
// retire (lgkmcnt), but global prefetch loads stay in flight across it (T4).
__device__ __forceinline__ void lds_barrier() {
  asm volatile("s_waitcnt lgkmcnt(0)" ::: "memory");
  __builtin_amdgcn_sched_barrier(0);
  __builtin_amdgcn_s_barrier();
  __builtin_amdgcn_sched_barrier(0);
}

// LDS elem index for [rows][32] bf16 tiles (64-B rows, 4x 16B chunks).
// chunk ^= (r>>1)&3  (r7 map, best measured config).
__device__ __forceinline__ int sidx(int r, int k) {
  return (r << 5) + ((((k >> 3) ^ ((r >> 1) & 3)) << 3) | (k & 7));
}

// ---------------- zero output + counts ----------------
__global__ __launch_bounds__(256) void zero_out_k(float4* __restrict__ out4,
                                                  int* __restrict__ counts) {
  size_t i = (size_t)blockIdx.x * 256 + threadIdx.x;
  out4[i] = make_float4(0.f, 0.f, 0.f, 0.f);
  if (blockIdx.x == 0 && threadIdx.x < NBANKS) counts[threadIdx.x] = 0;
}

// ---------------- X f32 -> bf16 pre-convert ----------------
__global__ __launch_bounds__(256) void cvtx_k(const float* __restrict__ X,
                                              unsigned short* __restrict__ Xb) {
  const size_t i = ((size_t)blockIdx.x * 256 + threadIdx.x) * 8;
  const float4 a = *(const float4*)(X + i);
  const float4 b = *(const float4*)(X + i + 4);
  u32x4 v;
  v[0] = cvtpk(a.x, a.y); v[1] = cvtpk(a.z, a.w);
  v[2] = cvtpk(b.x, b.y); v[3] = cvtpk(b.z, b.w);
  *(u32x4*)(Xb + i) = v;
}

// ---------------- router ----------------
__global__ __launch_bounds__(64) void router_k(const float* __restrict__ x,
                                               const float* __restrict__ Wr,
                                               const float* __restrict__ br,
                                               int* __restrict__ topIdx,
                                               float* __restrict__ topGate) {
  const int t = blockIdx.x;
  const int l = threadIdx.x;
  const float* xr = x + (size_t)t * D_MODEL;

  float acc[NBANKS];
#pragma unroll
  for (int e = 0; e < NBANKS; ++e) acc[e] = 0.f;

  for (int d = l; d < D_MODEL; d += 64) {
    const float xv = xr[d];
    const float* wrow = Wr + (size_t)d * NBANKS;
#pragma unroll
    for (int e = 0; e < NBANKS; ++e) acc[e] += xv * wrow[e];
  }
#pragma unroll
  for (int e = 0; e < NBANKS; ++e) {
#pragma unroll
    for (int m = 1; m < 64; m <<= 1) acc[e] += __shfl_xor(acc[e], m, 64);
  }
#pragma unroll
  for (int e = 0; e < NBANKS; ++e) acc[e] += br[e];

  if (l == 0) {
    float mx = acc[0];
#pragma unroll
    for (int e = 1; e < NBANKS; ++e) mx = fmaxf(mx, acc[e]);
    float p[NBANKS];
    float s = 0.f;
#pragma unroll
    for (int e = 0; e < NBANKS; ++e) { p[e] = expf(acc[e] - mx); s += p[e]; }
    int i0 = 0; float v0 = p[0];
#pragma unroll
    for (int e = 1; e < NBANKS; ++e) if (p[e] > v0) { v0 = p[e]; i0 = e; }
    int i1 = -1; float v1 = -1.f;
#pragma unroll
    for (int e = 0; e < NBANKS; ++e) if (e != i0 && p[e] > v1) { v1 = p[e]; i1 = e; }
    const float inv = 1.f / s;
    topIdx[2 * t]     = i0;
    topIdx[2 * t + 1] = i1;
    topGate[2 * t]     = v0 * inv;
    topGate[2 * t + 1] = v1 * inv;
  }
}

// ---------------- build per-bank token lists ----------------
__global__ __launch_bounds__(256) void build_lists_k(const int* __restrict__ topIdx,
                                                     const float* __restrict__ topGate,
                                                     int* __restrict__ counts,
                                                     int* __restrict__ rowlist,
                                                     float* __restrict__ gatelist) {
  const int t = blockIdx.x * 256 + threadIdx.x;
  if (t >= NTOK) return;
#pragma unroll
  for (int k = 0; k < 2; ++k) {
    const int e = topIdx[2 * t + k];
    const int p = atomicAdd(&counts[e], 1);
    rowlist[e * NTOK + p]  = t;
    gatelist[e * NTOK + p] = topGate[2 * t + k];
  }
}

// scan + build compacted live-tile list (e, m0) so live blocks dispatch first
__global__ void scan_k(const int* __restrict__ counts, int* __restrict__ bankOff,
                       int* __restrict__ tileE, int* __restrict__ tileM,
                       int* __restrict__ nT) {
  if (threadIdx.x == 0) {
    int s = 0;
    int t = 0;
    for (int e = 0; e < NBANKS; ++e) {
      bankOff[e] = s;
      const int c = counts[e];
      s += c;
      for (int m = 0; m < c; m += BM) {
        tileE[t] = e;
        tileM[t] = m;
        ++t;
      }
    }
    bankOff[NBANKS] = s;
    nT[0] = t;
  }
}

// ---------------- GEMM1: H = relu(gather(Xb) @ W1[e] + b1[e]) ----------------
// r14 structure + raw lds_barrier (prefetch loads span barriers).
__global__ __launch_bounds__(256, 2) void gemm1_k(const unsigned short* __restrict__ Xb,
                                                  const float* __restrict__ W1,
                                                  const float* __restrict__ b1,
                                                  const int* __restrict__ counts,
                                                  const int* __restrict__ bankOff,
                                                  const int* __restrict__ rowlist,
                                                  const int* __restrict__ tileE,
                                                  const int* __restrict__ tileM,
                                                  const int* __restrict__ nT,
                                                  unsigned short* __restrict__ H) {
  const int tI = blockIdx.y;
  if (tI >= nT[0]) return;
  const int e   = tileE[tI];
  const int m0  = tileM[tI];
  const int cnt = counts[e];
  const int n0  = blockIdx.x * BN;

  const int tid  = threadIdx.x;
  const int lane = tid & 63;
  const int w    = tid >> 6;
  const int wm   = (w >> 1) * 64;
  const int wn   = (w & 1) * 64;

  __shared__ unsigned short Xs[2 * TBUF];
  __shared__ unsigned short Ws[2 * TBUF];

  // A staging: row = tid>>1, 16 bf16 at ak
  const int arow = tid >> 1;
  const int ak   = (tid & 1) * 16;
  const int gi   = min(m0 + arow, cnt - 1);
  const int tok  = rowlist[e * NTOK + gi];
  const unsigned short* Asrc = Xb + (size_t)tok * D_MODEL + ak;
  const int xo0 = sidx(arow, ak);
  const int xo1 = sidx(arow, ak + 8);

  // B staging: 4n x 4k micro-transpose; n4 = 4*(tid&31), k4 = 4*(tid>>5)
  const int n4 = 4 * (tid & 31);
  const int k4 = 4 * (tid >> 5);
  const float* Bsrc = W1 + (size_t)e * D_MODEL * D_HIDDEN + (size_t)k4 * D_HIDDEN + n0 + n4;
  int wo[4];
#pragma unroll
  for (int i = 0; i < 4; ++i) wo[i] = sidx(n4 + i, k4);

  const int fr = lane & 15;
  const int fc = (lane >> 4) * 8;
  int aoff[4], boff[4];
#pragma unroll
  for (int i = 0; i < 4; ++i) {
    aoff[i] = sidx(wm + i * 16 + fr, fc);
    boff[i] = sidx(wn + i * 16 + fr, fc);
  }

  // two independent in-flight register sets (rule #20: named, static)
  bf16x8 pa0, pa1, qa0, qa1;
  float pb[4][4], qb[4][4];

  f32x4 acc[4][4];
#pragma unroll
  for (int i = 0; i < 4; ++i)
#pragma unroll
    for (int j = 0; j < 4; ++j)
#pragma unroll
      for (int r = 0; r < 4; ++r) acc[i][j][r] = 0.f;

  unsigned short* xc = &Xs[0];       unsigned short* wc = &Ws[0];   // even tiles
  unsigned short* xn = &Xs[TBUF];    unsigned short* wn_ = &Ws[TBUF]; // odd tiles

  auto LOADP = [&](int t) {
    const unsigned short* ap = Asrc + t * BK;
    pa0 = *(const bf16x8*)(ap);
    pa1 = *(const bf16x8*)(ap + 8);
    const float* bp = Bsrc + (size_t)t * BK * D_HIDDEN;
#pragma unroll
    for (int kk = 0; kk < 4; ++kk)
      *(float4*)&pb[kk][0] = *(const float4*)(bp + (size_t)kk * D_HIDDEN);
  };
  auto LOADQ = [&](int t) {
    const unsigned short* ap = Asrc + t * BK;
    qa0 = *(const bf16x8*)(ap);
    qa1 = *(const bf16x8*)(ap + 8);
    const float* bp = Bsrc + (size_t)t * BK * D_HIDDEN;
#pragma unroll
    for (int kk = 0; kk < 4; ++kk)
      *(float4*)&qb[kk][0] = *(const float4*)(bp + (size_t)kk * D_HIDDEN);
  };
  auto WRITEP = [&](unsigned short* xs, unsigned short* ws) {
    *(bf16x8*)(xs + xo0) = pa0;
    *(bf16x8*)(xs + xo1) = pa1;
#pragma unroll
    for (int i = 0; i < 4; ++i) {
      u32x2 v;
      v[0] = cvtpk(pb[0][i], pb[1][i]);
      v[1] = cvtpk(pb[2][i], pb[3][i]);
      *(u32x2*)(ws + wo[i]) = v;
    }
  };
  auto WRITEQ = [&](unsigned short* xs, unsigned short* ws) {
    *(bf16x8*)(xs + xo0) = qa0;
    *(bf16x8*)(xs + xo1) = qa1;
#pragma unroll
    for (int i = 0; i < 4; ++i) {
      u32x2 v;
      v[0] = cvtpk(qb[0][i], qb[1][i]);
      v[1] = cvtpk(qb[2][i], qb[3][i]);
      *(u32x2*)(ws + wo[i]) = v;
    }
  };
  auto COMPUTE = [&](const unsigned short* xs, const unsigned short* ws) {
    bf16x8 af[4], bb[4];
#pragma unroll
    for (int mb = 0; mb < 4; ++mb) af[mb] = *(const bf16x8*)(xs + aoff[mb]);
#pragma unroll
    for (int nb = 0; nb < 4; ++nb) bb[nb] = *(const bf16x8*)(ws + boff[nb]);
#pragma unroll
    for (int mb = 0; mb < 4; ++mb)
#pragma unroll
      for (int nb = 0; nb < 4; ++nb)
        acc[mb][nb] = __builtin_amdgcn_mfma_f32_16x16x32_bf16(af[mb], bb[nb], acc[mb][nb], 0, 0, 0);
  };

  const int NT = D_MODEL / BK;   // 32 (even)
  LOADP(0);
  LOADQ(1);
  WRITEP(xc, wc);                // tile 0 -> buf0; P free
  lds_barrier();
#pragma unroll 1
  for (int t = 0; t < NT; t += 2) {
    if (t + 2 < NT) LOADP(t + 2);              // stays in flight across barriers
    __builtin_amdgcn_sched_barrier(0);
    COMPUTE(xc, wc);                           // tile t (buf0)
    WRITEQ(xn, wn_);                           // tile t+1 -> buf1; Q free
    lds_barrier();
    if (t + 3 < NT) LOADQ(t + 3);              // stays in flight across barriers
    __builtin_amdgcn_sched_barrier(0);
    COMPUTE(xn, wn_);                          // tile t+1 (buf1)
    if (t + 2 < NT) WRITEP(xc, wc);            // tile t+2 -> buf0; P free
    lds_barrier();
  }

  // epilogue: relu(acc + b1) -> H (bf16)
  const int hb = bankOff[e] + m0;
  const int rq = (lane >> 4) * 4;
#pragma unroll
  for (int nb = 0; nb < 4; ++nb) {
    const int col = n0 + wn + nb * 16 + fr;
    const float bias = b1[e * D_HIDDEN + col];
#pragma unroll
    for (int mb = 0; mb < 4; ++mb)
#pragma unroll
      for (int r = 0; r < 4; ++r) {
        const int rowT = wm + mb * 16 + rq + r;
        if (m0 + rowT < cnt) {
          float v = acc[mb][nb][r] + bias;
          v = fmaxf(v, 0.f);
          H[(size_t)(hb + rowT) * D_HIDDEN + col] = f2bf(v);
        }
      }
  }
}

// ---------------- GEMM2: out += gate * (H @ W2[e] + b2[e]), K-split x4 ----
// grid.y = 4*tI + kc (live tiles first); depth-2 prefetch + raw lds_barrier.
__global__ __launch_bounds__(256, 2) void gemm2_k(const unsigned short* __restrict__ H,
                                                  const float* __restrict__ W2,
                                                  const float* __restrict__ b2,
                                                  const int* __restrict__ counts,
                                                  const int* __restrict__ bankOff,
                                                  const int* __restrict__ rowlist,
                                                  const float* __restrict__ gatelist,
                                                  const int* __restrict__ tileE,
                                                  const int* __restrict__ tileM,
                                                  const int* __restrict__ nT,
                                                  float* __restrict__ out) {
  const int tI = blockIdx.y >> 2;
  const int kc = blockIdx.y & 3;
  if (tI >= nT[0]) return;
  const int e   = tileE[tI];
  const int m0  = tileM[tI];
  const int cnt = counts[e];
  const int n0  = blockIdx.x * BN;
  const int kc0 = kc * (D_HIDDEN / KS2);   // 0, 1024, 2048, 3072

  const int tid  = threadIdx.x;
  const int lane = tid & 63;
  const int w    = tid >> 6;
  const int wm   = (w >> 1) * 64;
  const int wn   = (w & 1) * 64;

  __shared__ unsigned short Xs[2 * TBUF];
  __shared__ unsigned short Ws[2 * TBUF];

  const int arow = tid >> 1;
  const int ak   = (tid & 1) * 16;
  const int hb   = bankOff[e];
  const int gi   = hb + min(m0 + arow, cnt - 1);
  const unsigned short* Asrc = H + (size_t)gi * D_HIDDEN + kc0 + ak;
  const int xo0 = sidx(arow, ak);
  const int xo1 = sidx(arow, ak + 8);

  const int n4 = 4 * (tid & 31);
  const int k4 = 4 * (tid >> 5);
  const float* Bsrc = W2 + (size_t)e * D_HIDDEN * D_MODEL + (size_t)(kc0 + k4) * D_MODEL + n0 + n4;
  int wo[4];
#pragma unroll
  for (int i = 0; i < 4; ++i) wo[i] = sidx(n4 + i, k4);

  const int fr = lane & 15;
  const int fc = (lane >> 4) * 8;
  int aoff[4], boff[4];
#pragma unroll
  for (int i = 0; i < 4; ++i) {
    aoff[i] = sidx(wm + i * 16 + fr, fc);
    boff[i] = sidx(wn + i * 16 + fr, fc);
  }

  bf16x8 pa0, pa1, qa0, qa1;
  float pb[4][4], qb[4][4];

  f32x4 acc[4][4];
#pragma unroll
  for (int i = 0; i < 4; ++i)
#pragma unroll
    for (int j = 0; j < 4; ++j)
#pragma unroll
      for (int r = 0; r < 4; ++r) acc[i][j][r] = 0.f;

  unsigned short* xc = &Xs[0];       unsigned short* wc = &Ws[0];
  unsigned short* xn = &Xs[TBUF];    unsigned short* wn_ = &Ws[TBUF];

  auto LOADP = [&](int t) {
    const unsigned short* ap = Asrc + t * BK;
    pa0 = *(const bf16x8*)(ap);
    pa1 = *(const bf16x8*)(ap + 8);
    const float* bp = Bsrc + (size_t)t * BK * D_MODEL;
#pragma unroll
    for (int kk = 0; kk < 4; ++kk)
      *(float4*)&pb[kk][0] = *(const float4*)(bp + (size_t)kk * D_MODEL);
  };
  auto LOADQ = [&](int t) {
    const unsigned short* ap = Asrc + t * BK;
    qa0 = *(const bf16x8*)(ap);
    qa1 = *(const bf16x8*)(ap + 8);
    const float* bp = Bsrc + (size_t)t * BK * D_MODEL;
#pragma unroll
    for (int kk = 0; kk < 4; ++kk)
      *(float4*)&qb[kk][0] = *(const float4*)(bp + (size_t)kk * D_MODEL);
  };
  auto WRITEP = [&](unsigned short* xs, unsigned short* ws) {
    *(bf16x8*)(xs + xo0) = pa0;
    *(bf16x8*)(xs + xo1) = pa1;
#pragma unroll
    for (int i = 0; i < 4; ++i) {
      u32x2 v;
      v[0] = cvtpk(pb[0][i], pb[1][i]);
      v[1] = cvtpk(pb[2][i], pb[3][i]);
      *(u32x2*)(ws + wo[i]) = v;
    }
  };
  auto WRITEQ = [&](unsigned short* xs, unsigned short* ws) {
    *(bf16x8*)(xs + xo0) = qa0;
    *(bf16x8*)(xs + xo1) = qa1;
#pragma unroll
    for (int i = 0; i < 4; ++i) {
      u32x2 v;
      v[0] = cvtpk(qb[0][i], qb[1][i]);
      v[1] = cvtpk(qb[2][i], qb[3][i]);
      *(u32x2*)(ws + wo[i]) = v;
    }
  };
  auto COMPUTE = [&](const unsigned short* xs, const unsigned short* ws) {
    bf16x8 af[4], bb[4];
#pragma unroll
    for (int mb = 0; mb < 4; ++mb) af[mb] = *(const bf16x8*)(xs + aoff[mb]);
#pragma unroll
    for (int nb = 0; nb < 4; ++nb) bb[nb] = *(const bf16x8*)(ws + boff[nb]);
#pragma unroll
    for (int mb = 0; mb < 4; ++mb)
#pragma unroll
      for (int nb = 0; nb < 4; ++nb)
        acc[mb][nb] = __builtin_amdgcn_mfma_f32_16x16x32_bf16(af[mb], bb[nb], acc[mb][nb], 0, 0, 0);
  };

  const int NT = (D_HIDDEN / KS2) / BK;   // 32 (even)
  LOADP(0);
  LOADQ(1);
  WRITEP(xc, wc);
  lds_barrier();
#pragma unroll 1
  for (int t = 0; t < NT; t += 2) {
    if (t + 2 < NT) LOADP(t + 2);
    __builtin_amdgcn_sched_barrier(0);
    COMPUTE(xc, wc);
    WRITEQ(xn, wn_);
    lds_barrier();
    if (t + 3 < NT) LOADQ(t + 3);
    __builtin_amdgcn_sched_barrier(0);
    COMPUTE(xn, wn_);
    if (t + 2 < NT) WRITEP(xc, wc);
    lds_barrier();
  }

  // epilogue: out[tok] += gate * (acc [+ b2 if kc==0])
  const int rq = (lane >> 4) * 4;
  float bias[4];
#pragma unroll
  for (int nb = 0; nb < 4; ++nb)
    bias[nb] = (kc == 0) ? b2[e * D_MODEL + n0 + wn + nb * 16 + fr] : 0.f;

#pragma unroll
  for (int mb = 0; mb < 4; ++mb)
#pragma unroll
    for (int r = 0; r < 4; ++r) {
      const int rowT = wm + mb * 16 + rq + r;
      if (m0 + rowT < cnt) {
        const int si = e * NTOK + m0 + rowT;
        const int tok = rowlist[si];
        const float g = gatelist[si];
        float* orow = out + (size_t)tok * D_MODEL;
#pragma unroll
        for (int nb = 0; nb < 4; ++nb) {
          const int col = n0 + wn + nb * 16 + fr;
          atomicAdd(&orow[col], g * (acc[mb][nb][r] + bias[nb]));
        }
      }
    }
}

// ---------------- launch ----------------
extern "C" void kernel_launch(void* const* d_in, const int* in_sizes, int n_in,
                              void* d_out, int out_size, void* d_ws, size_t ws_size,
                              hipStream_t stream) {
  const float* X  = (const float*)d_in[0];
  const float* Wr = (const float*)d_in[1];
  const float* br = (const float*)d_in[2];
  const float* W1 = (const float*)d_in[3];
  const float* b1 = (const float*)d_in[4];
  const float* W2 = (const float*)d_in[5];
  const float* b2 = (const float*)d_in[6];
  float* out = (float*)d_out;

  char* w = (char*)d_ws;
  int*   topIdx   = (int*)(w);                                   // 32 KB
  float* topGate  = (float*)(w + (32 << 10));                    // 32 KB
  int*   counts   = (int*)(w + (64 << 10));                      // 64 B
  int*   bankOff  = (int*)(w + (64 << 10) + 256);                // 68 B
  int*   rowlist  = (int*)(w + (66 << 10));                      // 256 KB
  float* gatelist = (float*)(w + (66 << 10) + NBANKS * NTOK * 4);// 256 KB
  int*   tileE    = (int*)(w + (600 << 10));                     // 2 KB
  int*   tileM    = (int*)(w + (604 << 10));                     // 2 KB
  int*   nT       = (int*)(w + (608 << 10));                     // 4 B
  unsigned short* Xb = (unsigned short*)(w + (1 << 20));         // 8 MiB
  unsigned short* H  = (unsigned short*)(w + (16 << 20));        // 64 MiB

  const size_t needed = (size_t)(16 << 20) + (size_t)(NTOK * 2) * D_HIDDEN * 2;
  if (ws_size < needed) return;

  zero_out_k<<<dim3(4096), dim3(256), 0, stream>>>((float4*)out, counts);
  cvtx_k<<<dim3(NTOK * D_MODEL / 8 / 256), dim3(256), 0, stream>>>(X, Xb);
  router_k<<<dim3(NTOK), dim3(64), 0, stream>>>(X, Wr, br, topIdx, topGate);
  build_lists_k<<<dim3(16), dim3(256), 0, stream>>>(topIdx, topGate, counts, rowlist, gatelist);
  scan_k<<<dim3(1), dim3(64), 0, stream>>>(counts, bankOff, tileE, tileM, nT);
  gemm1_k<<<dim3(D_HIDDEN / BN, MAXT), dim3(256), 0, stream>>>(
      Xb, W1, b1, counts, bankOff, rowlist, tileE, tileM, nT, H);
  gemm2_k<<<dim3(D_MODEL / BN, MAXT * KS2), dim3(256), 0, stream>>>(
      H, W2, b2, counts, bankOff, rowlist, gatelist, tileE, tileM, nT, out);
}